// Round 2
// baseline (781.613 us; speedup 1.0000x reference)
//
#include <hip/hip_runtime.h>

#define NB 4
#define IH 512
#define IW 512
#define FH 256
#define FW 256
#define CF 96
#define C1 99
#define HWI (IH*IW)     /* 262144 */
#define HWF (FH*FW)     /* 65536  */
#define LDK 40          /* padded K stride (shorts) in LDS: 80B */

typedef short s8v __attribute__((ext_vector_type(8)));
typedef short s4v __attribute__((ext_vector_type(4)));
typedef float f4v __attribute__((ext_vector_type(4)));
typedef float f2v __attribute__((ext_vector_type(2), aligned(4)));  /* 4B-aligned pair load */

static __device__ __forceinline__ float sigmoidf_(float x) {
    return 1.0f / (1.0f + __expf(-x));
}
static __device__ __forceinline__ unsigned short f2bf(float f) {
    unsigned int u = __float_as_uint(f);
    unsigned int r = (u + 0x7fffu + ((u >> 16) & 1u)) >> 16;
    return (unsigned short)r;
}
static __device__ __forceinline__ float bf2f(short s) {
    unsigned int u = ((unsigned int)(unsigned short)s) << 16;
    return __uint_as_float(u);
}

// ---------------------------------------------------------------------------
// Pass 1 of local_kernel_warp (validated R1)
// ---------------------------------------------------------------------------
__global__ __launch_bounds__(256)
void lkw_row_kernel(const float* __restrict__ img,
                    const float* __restrict__ flow,
                    const float* __restrict__ kp,
                    float* __restrict__ img_row) {
    int idx = blockIdx.x * blockDim.x + threadIdx.x;
    if (idx >= NB * HWI) return;
    int w = idx & (IW - 1);
    int h = (idx >> 9) & (IH - 1);
    int b = idx >> 18;

    const float* kpb = kp + (size_t)b * 11 * HWI + h * IW + w;
    float p[5];
    float m = -1e30f;
    #pragma unroll
    for (int k = 0; k < 5; k++) { p[k] = kpb[k * HWI]; m = fmaxf(m, p[k]); }
    float s = 0.f;
    #pragma unroll
    for (int k = 0; k < 5; k++) { p[k] = __expf(p[k] - m); s += p[k]; }
    float invs = 1.f / s;
    float a = sigmoidf_(kpb[10 * HWI]) + 0.5f;
    float inva = 1.f / a;

    float fx = flow[((size_t)b * 2 + 0) * HWI + h * IW + w];
    float fy = flow[((size_t)b * 2 + 1) * HWI + h * IW + w];

    float y = (float)h + 0.5f * fy;
    y = fminf(fmaxf(y, 0.f), (float)(IH - 1));
    float y0f = floorf(y);
    int y0 = (int)y0f;
    int y1 = min(y0 + 1, IH - 1);
    float wy = y - y0f;

    float xbase = (float)w + 0.5f * fx;
    const float sc = (float)(IW - 1) / (float)IW;

    const float* imb = img + (size_t)b * 3 * HWI;
    float acc0 = 0.f, acc1 = 0.f, acc2 = 0.f;
    #pragma unroll
    for (int k = 0; k < 5; k++) {
        float x = xbase + (float)(k - 2) * inva * sc;
        x = fminf(fmaxf(x, 0.f), (float)(IW - 1));
        float x0f = floorf(x);
        int x0 = (int)x0f;
        int x1 = min(x0 + 1, IW - 1);
        float wx = x - x0f;
        float wk = p[k] * invs;
        float w00 = (1.f - wx) * (1.f - wy) * wk;
        float w01 = wx * (1.f - wy) * wk;
        float w10 = (1.f - wx) * wy * wk;
        float w11 = wx * wy * wk;
        int i00 = y0 * IW + x0, i01 = y0 * IW + x1;
        int i10 = y1 * IW + x0, i11 = y1 * IW + x1;
        acc0 += w00 * imb[i00] + w01 * imb[i01] + w10 * imb[i10] + w11 * imb[i11];
        acc1 += w00 * imb[HWI + i00] + w01 * imb[HWI + i01] + w10 * imb[HWI + i10] + w11 * imb[HWI + i11];
        acc2 += w00 * imb[2 * HWI + i00] + w01 * imb[2 * HWI + i01] + w10 * imb[2 * HWI + i10] + w11 * imb[2 * HWI + i11];
    }
    img_row[(size_t)b * 3 * HWI + h * IW + w] = acc0;
    img_row[(size_t)b * 3 * HWI + HWI + h * IW + w] = acc1;
    img_row[(size_t)b * 3 * HWI + 2 * HWI + h * IW + w] = acc2;
}

// ---------------------------------------------------------------------------
// Pass 2 (validated R1)
// ---------------------------------------------------------------------------
__global__ __launch_bounds__(256)
void lkw_col_kernel(const float* __restrict__ img_row,
                    const float* __restrict__ kp,
                    float* __restrict__ out1) {
    int idx = blockIdx.x * blockDim.x + threadIdx.x;
    if (idx >= NB * HWI) return;
    int w = idx & (IW - 1);
    int h = (idx >> 9) & (IH - 1);
    int b = idx >> 18;

    const float* kpb = kp + (size_t)b * 11 * HWI + h * IW + w;
    float p[5];
    float m = -1e30f;
    #pragma unroll
    for (int k = 0; k < 5; k++) { p[k] = kpb[(5 + k) * HWI]; m = fmaxf(m, p[k]); }
    float s = 0.f;
    #pragma unroll
    for (int k = 0; k < 5; k++) { p[k] = __expf(p[k] - m); s += p[k]; }
    float invs = 1.f / s;
    float a = sigmoidf_(kpb[10 * HWI]) + 0.5f;

    const float sc = (float)(IH - 1) / (float)IH;
    const float* irb = img_row + (size_t)b * 3 * HWI;
    float acc0 = 0.f, acc1 = 0.f, acc2 = 0.f;
    #pragma unroll
    for (int k = 0; k < 5; k++) {
        float y = (float)h + (float)(k - 2) * a * sc;
        y = fminf(fmaxf(y, 0.f), (float)(IH - 1));
        float y0f = floorf(y);
        int y0 = (int)y0f;
        int y1 = min(y0 + 1, IH - 1);
        float wy = y - y0f;
        float wk = p[k] * invs;
        float w0 = (1.f - wy) * wk, w1 = wy * wk;
        int i0 = y0 * IW + w, i1 = y1 * IW + w;
        acc0 += w0 * irb[i0] + w1 * irb[i1];
        acc1 += w0 * irb[HWI + i0] + w1 * irb[HWI + i1];
        acc2 += w0 * irb[2 * HWI + i0] + w1 * irb[2 * HWI + i1];
    }
    out1[(size_t)b * 3 * HWI + h * IW + w] = acc0;
    out1[(size_t)b * 3 * HWI + HWI + h * IW + w] = acc1;
    out1[(size_t)b * 3 * HWI + 2 * HWI + h * IW + w] = acc2;
}

// ---------------------------------------------------------------------------
// antialiased 2x downsample taps (validated R1)
// ---------------------------------------------------------------------------
static __device__ __forceinline__ void ds_taps(int i, int n_in, int t[4], float wt[4]) {
    int n_out = n_in >> 1;
    if (i == 0) {
        t[0] = 0; t[1] = 0; t[2] = 1; t[3] = 2;
        wt[0] = 0.f; wt[1] = 3.f / 7.f; wt[2] = 3.f / 7.f; wt[3] = 1.f / 7.f;
    } else if (i == n_out - 1) {
        t[0] = n_in - 3; t[1] = n_in - 2; t[2] = n_in - 1; t[3] = n_in - 1;
        wt[0] = 1.f / 7.f; wt[1] = 3.f / 7.f; wt[2] = 3.f / 7.f; wt[3] = 0.f;
    } else {
        t[0] = 2 * i - 1; t[1] = 2 * i; t[2] = 2 * i + 1; t[3] = 2 * i + 2;
        wt[0] = 0.125f; wt[1] = 0.375f; wt[2] = 0.375f; wt[3] = 0.125f;
    }
}

__global__ __launch_bounds__(256)
void downsample2x_kernel(const float* __restrict__ src, float* __restrict__ dst,
                         int BC, float mul) {
    int idx = blockIdx.x * blockDim.x + threadIdx.x;
    if (idx >= BC * HWF) return;
    int j = idx & (FW - 1);
    int i = (idx >> 8) & (FH - 1);
    int bc = idx >> 16;

    int tx[4], ty[4];
    float wx[4], wy[4];
    ds_taps(j, IW, tx, wx);
    ds_taps(i, IH, ty, wy);
    const float* s = src + (size_t)bc * HWI;
    float acc = 0.f;
    #pragma unroll
    for (int a = 0; a < 4; a++) {
        if (wy[a] == 0.f) continue;
        const float* rp = s + (size_t)ty[a] * IW;
        float row = wx[0] * rp[tx[0]] + wx[1] * rp[tx[1]] + wx[2] * rp[tx[2]] + wx[3] * rp[tx[3]];
        acc += wy[a] * row;
    }
    dst[idx] = acc * mul;
}

// ---------------------------------------------------------------------------
// img downsample -> channels-last bf16 xin slots [96..128)
// ---------------------------------------------------------------------------
__global__ __launch_bounds__(256)
void imgdown_cl_kernel(const float* __restrict__ out1, short* __restrict__ xin) {
    int idx = blockIdx.x * blockDim.x + threadIdx.x;
    if (idx >= NB * HWF) return;
    int j = idx & (FW - 1);
    int i = (idx >> 8) & (FH - 1);
    int b = idx >> 16;

    int tx[4], ty[4];
    float wx[4], wy[4];
    ds_taps(j, IW, tx, wx);
    ds_taps(i, IH, ty, wy);
    const float* s = out1 + (size_t)b * 3 * HWI;
    float acc[3] = {0.f, 0.f, 0.f};
    #pragma unroll
    for (int a = 0; a < 4; a++) {
        if (wy[a] == 0.f) continue;
        #pragma unroll
        for (int c = 0; c < 3; c++) {
            const float* rp = s + (size_t)c * HWI + (size_t)ty[a] * IW;
            float row = wx[0] * rp[tx[0]] + wx[1] * rp[tx[1]] + wx[2] * rp[tx[2]] + wx[3] * rp[tx[3]];
            acc[c] += wy[a] * row;
        }
    }
    short* dst = xin + ((size_t)(b * FH + i) * FW + j) * 128 + 96;
    s8v g0 = { (short)f2bf(acc[0]), (short)f2bf(acc[1]), (short)f2bf(acc[2]), 0, 0, 0, 0, 0 };
    s8v z  = { 0, 0, 0, 0, 0, 0, 0, 0 };
    *(s8v*)(dst)      = g0;
    *(s8v*)(dst + 8)  = z;
    *(s8v*)(dst + 16) = z;
    *(s8v*)(dst + 24) = z;
}

// ---------------------------------------------------------------------------
// feat [B][96][H][W] fp32 -> featT [B][H][W][96] channels-last (validated R1)
// ---------------------------------------------------------------------------
template <int BF>
__global__ __launch_bounds__(256)
void feat_cl_kernel(const float* __restrict__ feat, void* __restrict__ featT) {
    __shared__ float tile[64 * 97];
    int blk = blockIdx.x;                 // NB * (HWF/64) = 4096
    int b = blk >> 10;                    // HWF/64 = 1024
    int p0 = (blk & 1023) << 6;
    int t = threadIdx.x;
    {
        int px = t & 63, cq = t >> 6;     // cq: 4 groups of 24 channels
        const float* src = feat + (size_t)b * CF * HWF + p0 + px;
        #pragma unroll
        for (int k = 0; k < 24; k++) {
            int c = cq * 24 + k;
            tile[px * 97 + c] = src[(size_t)c * HWF];
        }
    }
    __syncthreads();
    int pxo = t >> 2, co = (t & 3) * 24;  // 4 threads per pixel, 24 ch each
    const float* trow = &tile[pxo * 97 + co];
    size_t obase = ((size_t)(b * HWF) + p0 + pxo) * 96 + co;
    if (BF) {
        short* dst = (short*)featT + obase;
        #pragma unroll
        for (int q = 0; q < 3; q++) {
            s8v pk;
            #pragma unroll
            for (int e = 0; e < 8; e++) pk[e] = (short)f2bf(trow[q * 8 + e]);
            *(s8v*)(dst + q * 8) = pk;
        }
    } else {
        float* dst = (float*)featT + obase;
        #pragma unroll
        for (int q = 0; q < 6; q++) {
            f4v vv = { trow[q * 4 + 0], trow[q * 4 + 1], trow[q * 4 + 2], trow[q * 4 + 3] };
            *(f4v*)(dst + q * 4) = vv;
        }
    }
}

// ---------------------------------------------------------------------------
// backward_warp(features) v3 over channels-last featT (validated R1)
// ---------------------------------------------------------------------------
template <int BF>
__global__ __launch_bounds__(256)
void warp_feat_cl2_kernel(const void* __restrict__ featT,
                          const float* __restrict__ flow_s,
                          float* __restrict__ wfeat,
                          short* __restrict__ xin) {
    int t = blockIdx.x * 256 + threadIdx.x;   // [0, NB*HWF*8)
    int g = t & 7;                            // channel group: 12 channels
    int pix = t >> 3;                         // [0, NB*HWF)
    int j = pix & (FW - 1);
    int i = (pix >> 8) & (FH - 1);
    int b = pix >> 16;

    float fx = flow_s[((size_t)b * 2 + 0) * HWF + i * FW + j];
    float fy = flow_s[((size_t)b * 2 + 1) * HWF + i * FW + j];
    float u = (float)j + 0.5f * fx;
    float v = (float)i + 0.5f * fy;
    bool valid = (u >= 0.f) && (u <= (float)(FW - 1)) && (v >= 0.f) && (v <= (float)(FH - 1));
    float x = fminf(fmaxf(u, 0.f), (float)(FW - 1));
    float y = fminf(fmaxf(v, 0.f), (float)(FH - 1));
    int x0 = min((int)x, FW - 2);
    int y0 = min((int)y, FH - 2);
    float wxf = x - (float)x0, wyf = y - (float)y0;
    float w00 = (1.f - wxf) * (1.f - wyf), w01 = wxf * (1.f - wyf);
    float w10 = (1.f - wxf) * wyf, w11 = wxf * wyf;
    if (!valid) { w00 = w01 = w10 = w11 = 0.f; }

    size_t base = ((size_t)(b * HWF) + (size_t)y0 * FW + x0) * 96 + g * 12;
    float vals[12];
    if (BF) {
        const short* fp = (const short*)featT + base;
        #pragma unroll
        for (int q = 0; q < 3; q++) {
            s4v a0 = *(const s4v*)(fp + q * 4);
            s4v a1 = *(const s4v*)(fp + 96 + q * 4);
            s4v a2 = *(const s4v*)(fp + 96 * FW + q * 4);
            s4v a3 = *(const s4v*)(fp + 96 * FW + 96 + q * 4);
            #pragma unroll
            for (int e = 0; e < 4; e++)
                vals[q * 4 + e] = w00 * bf2f(a0[e]) + w01 * bf2f(a1[e])
                                + w10 * bf2f(a2[e]) + w11 * bf2f(a3[e]);
        }
    } else {
        const float* fp = (const float*)featT + base;
        #pragma unroll
        for (int q = 0; q < 3; q++) {
            f4v a0 = *(const f4v*)(fp + q * 4);
            f4v a1 = *(const f4v*)(fp + 96 + q * 4);
            f4v a2 = *(const f4v*)(fp + 96 * FW + q * 4);
            f4v a3 = *(const f4v*)(fp + 96 * FW + 96 + q * 4);
            #pragma unroll
            for (int e = 0; e < 4; e++)
                vals[q * 4 + e] = w00 * a0[e] + w01 * a1[e] + w10 * a2[e] + w11 * a3[e];
        }
    }

    float* ob = wfeat + ((size_t)b * CF + g * 12) * HWF + (size_t)i * FW + j;
    #pragma unroll
    for (int k = 0; k < 12; k++) ob[(size_t)k * HWF] = vals[k];

    short* xr = xin + (size_t)pix * 128 + g * 12;   // 24B per thread, 8B-aligned
    #pragma unroll
    for (int q2 = 0; q2 < 3; q2++) {
        s4v pk = { (short)f2bf(vals[q2 * 4 + 0]), (short)f2bf(vals[q2 * 4 + 1]),
                   (short)f2bf(vals[q2 * 4 + 2]), (short)f2bf(vals[q2 * 4 + 3]) };
        *(s4v*)(xr + q2 * 4) = pk;
    }
}

// ---------------------------------------------------------------------------
// backward_warp(features) v2 (validated R3) — kept as workspace-size fallback
// ---------------------------------------------------------------------------
__global__ __launch_bounds__(256)
void warp_feat_cl_kernel(const float* __restrict__ feat,
                         const float* __restrict__ flow_s,
                         float* __restrict__ wfeat,
                         short* __restrict__ xin) {
    int t = blockIdx.x * 256 + threadIdx.x;   // [0, NB*HWF*8)
    int g = t & 7;                            // channel group: 12 channels
    int pix = t >> 3;                         // [0, NB*HWF)
    int j = pix & (FW - 1);
    int i = (pix >> 8) & (FH - 1);
    int b = pix >> 16;

    float fx = flow_s[((size_t)b * 2 + 0) * HWF + i * FW + j];
    float fy = flow_s[((size_t)b * 2 + 1) * HWF + i * FW + j];
    float u = (float)j + 0.5f * fx;
    float v = (float)i + 0.5f * fy;
    bool valid = (u >= 0.f) && (u <= (float)(FW - 1)) && (v >= 0.f) && (v <= (float)(FH - 1));
    float x = fminf(fmaxf(u, 0.f), (float)(FW - 1));
    float y = fminf(fmaxf(v, 0.f), (float)(FH - 1));
    int x0 = min((int)x, FW - 2);
    int y0 = min((int)y, FH - 2);
    float wxf = x - (float)x0, wyf = y - (float)y0;
    float w00 = (1.f - wxf) * (1.f - wyf), w01 = wxf * (1.f - wyf);
    float w10 = (1.f - wxf) * wyf, w11 = wxf * wyf;
    if (!valid) { w00 = w01 = w10 = w11 = 0.f; }

    const float* fb = feat + ((size_t)b * CF + g * 12) * HWF + (size_t)y0 * FW + x0;
    float vals[12];
    #pragma unroll
    for (int k = 0; k < 12; k++) {
        const float* p = fb + (size_t)k * HWF;
        f2v r0 = *(const f2v*)p;
        f2v r1 = *(const f2v*)(p + FW);
        vals[k] = w00 * r0.x + w01 * r0.y + w10 * r1.x + w11 * r1.y;
    }

    float* ob = wfeat + ((size_t)b * CF + g * 12) * HWF + (size_t)i * FW + j;
    #pragma unroll
    for (int k = 0; k < 12; k++) ob[(size_t)k * HWF] = vals[k];

    short* xr = xin + (size_t)pix * 128 + g * 12;   // 24B per thread, 8B-aligned
    #pragma unroll
    for (int q2 = 0; q2 < 3; q2++) {
        s4v pk = { (short)f2bf(vals[q2 * 4 + 0]), (short)f2bf(vals[q2 * 4 + 1]),
                   (short)f2bf(vals[q2 * 4 + 2]), (short)f2bf(vals[q2 * 4 + 3]) };
        *(s4v*)(xr + q2 * 4) = pk;
    }
}

// ---------------------------------------------------------------------------
// Weight repack R2: w[co][ci][3][3] fp32 -> wA[kc][dy][dx][co][32ci] bf16.
// Per conv step (kc,dy) the A tile (3dx*96co*32ci = 18.4KB) is contiguous
// -> fully coalesced staging.
// ---------------------------------------------------------------------------
__global__ __launch_bounds__(256)
void cvt_w1_kernel(const float* __restrict__ w1, short* __restrict__ wA1) {
    int i = blockIdx.x * 256 + threadIdx.x;
    if (i >= 4 * 3 * 3 * 96 * 32) return;
    int cl = i & 31;
    int co = (i >> 5) % 96;
    int rest = i / 3072;
    int dx = rest % 3;
    int dy = (rest / 3) % 3;
    int kc = rest / 9;
    int ci = kc * 32 + cl;
    float v = (ci < C1) ? w1[((size_t)co * C1 + ci) * 9 + dy * 3 + dx] : 0.f;
    wA1[i] = (short)f2bf(v);
}
__global__ __launch_bounds__(256)
void cvt_w2_kernel(const float* __restrict__ w2, short* __restrict__ wA2) {
    int i = blockIdx.x * 256 + threadIdx.x;
    if (i >= 3 * 3 * 3 * 96 * 32) return;
    int cl = i & 31;
    int co = (i >> 5) % 96;
    int rest = i / 3072;
    int dx = rest % 3;
    int dy = (rest / 3) % 3;
    int kc = rest / 9;
    wA2[i] = (short)f2bf(w2[((size_t)co * CF + kc * 32 + cl) * 9 + dy * 3 + dx]);
}

// ---------------------------------------------------------------------------
// MFMA implicit-GEMM 3x3 conv v2.
// Loop order (kc, dy): B staged ONCE per step as a 130-px halo row; the 3 dx
// taps read LDS at shifted rows (no re-stage). 36 MFMAs per barrier pair
// (was 12), 12/9 stages (was 36/27). T14 async-stage: next step's global
// loads issue into regs before the compute phase. One-row-per-thread LDS
// staging: 80B-stride orbit covers all 32 banks minimally for b128 r/w.
// ---------------------------------------------------------------------------
template <int PASS>
__global__ __launch_bounds__(256)
void conv_mfma2_kernel(const short* __restrict__ X,    // [b][h][w][KSTR] bf16
                      const short* __restrict__ W,     // [KC][3dy][3dx][96co][32ci] bf16
                      const float* __restrict__ bias,
                      short* __restrict__ t1out,
                      float* __restrict__ out0) {
    constexpr int KSTR = (PASS == 1) ? 128 : 96;
    constexpr int KC = KSTR / 32;
    __shared__ short Als[288 * LDK];   // [dx*96+co][32ci]
    __shared__ short Bls[132 * LDK];   // [halo pixel 0..129][32ci]

    const int bx = blockIdx.x;
    const int w0 = (bx & 1) * 128;
    const int h  = (bx >> 1) & (FH - 1);
    const int b  = bx >> 9;

    const int tid = threadIdx.x;
    const int lane = tid & 63;
    const int wv = tid >> 6;
    const int ln = lane & 15;
    const int q  = lane >> 4;

    f4v acc[6][2];
    #pragma unroll
    for (int mt = 0; mt < 6; mt++)
        #pragma unroll
        for (int nt = 0; nt < 2; nt++)
            acc[mt][nt] = (f4v){0.f, 0.f, 0.f, 0.f};

    const short* Xb = X + (size_t)(b * FH) * FW * KSTR;
    const int wp = w0 - 1 + tid;                       // halo pixel for B staging
    const bool wok = (tid < 130) && (wp >= 0) && (wp < FW);

    float4 pa[4], pa2[4], pb[4];

    auto load_step = [&](int stepn, int kcn, int dyn) {
        const short* srcA = W + ((size_t)stepn * 288 + tid) * 32;
        pa[0] = *(const float4*)(srcA);
        pa[1] = *(const float4*)(srcA + 8);
        pa[2] = *(const float4*)(srcA + 16);
        pa[3] = *(const float4*)(srcA + 24);
        if (tid < 32) {
            const short* srcA2 = srcA + 256 * 32;
            pa2[0] = *(const float4*)(srcA2);
            pa2[1] = *(const float4*)(srcA2 + 8);
            pa2[2] = *(const float4*)(srcA2 + 16);
            pa2[3] = *(const float4*)(srcA2 + 24);
        }
        int hy = h + dyn - 1;
        if (wok && hy >= 0 && hy < FH) {
            const short* srcB = Xb + ((size_t)hy * FW + wp) * KSTR + kcn * 32;
            pb[0] = *(const float4*)(srcB);
            pb[1] = *(const float4*)(srcB + 8);
            pb[2] = *(const float4*)(srcB + 16);
            pb[3] = *(const float4*)(srcB + 24);
        } else {
            pb[0] = pb[1] = pb[2] = pb[3] = (float4){0.f, 0.f, 0.f, 0.f};
        }
    };

    load_step(0, 0, 0);

    int step = 0;
    for (int kc = 0; kc < KC; ++kc) {
        for (int dy = 0; dy < 3; ++dy, ++step) {
            __syncthreads();                         // prev compute's LDS reads done
            {
                short* dA = Als + tid * LDK;
                *(float4*)(dA)      = pa[0];
                *(float4*)(dA + 8)  = pa[1];
                *(float4*)(dA + 16) = pa[2];
                *(float4*)(dA + 24) = pa[3];
                if (tid < 32) {
                    short* dA2 = Als + (256 + tid) * LDK;
                    *(float4*)(dA2)      = pa2[0];
                    *(float4*)(dA2 + 8)  = pa2[1];
                    *(float4*)(dA2 + 16) = pa2[2];
                    *(float4*)(dA2 + 24) = pa2[3];
                }
                if (tid < 130) {
                    short* dB = Bls + tid * LDK;
                    *(float4*)(dB)      = pb[0];
                    *(float4*)(dB + 8)  = pb[1];
                    *(float4*)(dB + 16) = pb[2];
                    *(float4*)(dB + 24) = pb[3];
                }
            }
            __syncthreads();
            {   // issue next step's global loads; latency hides under MFMAs
                int ndy = dy + 1, nkc = kc;
                if (ndy == 3) { ndy = 0; nkc++; }
                if (nkc < KC) load_step(step + 1, nkc, ndy);
            }
            #pragma unroll
            for (int dx = 0; dx < 3; ++dx) {
                s8v bfr0 = *(const s8v*)(Bls + (wv * 32 + ln + dx) * LDK + q * 8);
                s8v bfr1 = *(const s8v*)(Bls + (wv * 32 + 16 + ln + dx) * LDK + q * 8);
                #pragma unroll
                for (int mt = 0; mt < 6; ++mt) {
                    s8v afr = *(const s8v*)(Als + (dx * 96 + mt * 16 + ln) * LDK + q * 8);
                    acc[mt][0] = __builtin_amdgcn_mfma_f32_16x16x32_bf16(afr, bfr0, acc[mt][0], 0, 0, 0);
                    acc[mt][1] = __builtin_amdgcn_mfma_f32_16x16x32_bf16(afr, bfr1, acc[mt][1], 0, 0, 0);
                }
            }
        }
    }

    if (PASS == 1) {
        const size_t rowbase = (size_t)(b * FH + h) * FW;
        #pragma unroll
        for (int nt = 0; nt < 2; ++nt) {
            int pos = w0 + wv * 32 + nt * 16 + ln;
            short* dst = t1out + (rowbase + pos) * CF;
            #pragma unroll
            for (int mt = 0; mt < 6; ++mt) {
                int co0 = mt * 16 + q * 4;
                s4v pk;
                #pragma unroll
                for (int r = 0; r < 4; ++r) {
                    float v = acc[mt][nt][r] + bias[co0 + r];
                    pk[r] = (short)f2bf(fmaxf(v, 0.f));
                }
                *(s4v*)(dst + co0) = pk;
            }
        }
    } else {
        #pragma unroll
        for (int nt = 0; nt < 2; ++nt) {
            int pos = w0 + wv * 32 + nt * 16 + ln;
            #pragma unroll
            for (int mt = 0; mt < 6; ++mt) {
                int co0 = mt * 16 + q * 4;
                #pragma unroll
                for (int r = 0; r < 4; ++r) {
                    size_t o = (size_t)(b * CF + co0 + r) * HWF + (size_t)h * FW + pos;
                    out0[o] += acc[mt][nt][r] + bias[co0 + r];
                }
            }
        }
    }
}

extern "C" void kernel_launch(void* const* d_in, const int* in_sizes, int n_in,
                              void* d_out, int out_size, void* d_ws, size_t ws_size,
                              hipStream_t stream) {
    const float* img  = (const float*)d_in[0];
    const float* feat = (const float*)d_in[1];
    const float* flow = (const float*)d_in[2];
    const float* kp   = (const float*)d_in[3];
    const float* w1   = (const float*)d_in[4];
    const float* b1   = (const float*)d_in[5];
    const float* w2   = (const float*)d_in[6];
    const float* b2   = (const float*)d_in[7];

    float* out0 = (float*)d_out;                       // [B,96,256,256] fp32
    float* out1 = out0 + (size_t)NB * CF * HWF;        // [B,3,512,512]  fp32

    char* wsb = (char*)d_ws;
    short* wA1 = (short*)wsb;                                   //   221,184 B
    short* wA2 = (short*)(wsb + 221184);                        //   165,888 B
    short* xin = (short*)(wsb + 387072);                        // 67,108,864 B [b][h][w][128]
    const size_t off_after_xin = 387072 + 67108864;             // 67,495,936

    const size_t FEATT_F32 = (size_t)NB * HWF * 96 * 4;         // 100,663,296
    const size_t FEATT_BF16 = (size_t)NB * HWF * 96 * 2;        //  50,331,648
    const size_t FLOW_B = 2097152;
    const size_t need_f32 = off_after_xin + FLOW_B + FEATT_F32; // 170,256,384
    const size_t need_b16 = off_after_xin + FLOW_B + FEATT_BF16;// 119,924,736

    int n_img = NB * HWI;
    hipLaunchKernelGGL(cvt_w1_kernel, dim3((9 * 96 * 128 + 255) / 256), dim3(256), 0, stream, w1, wA1);
    hipLaunchKernelGGL(cvt_w2_kernel, dim3((9 * 96 * 96 + 255) / 256), dim3(256), 0, stream, w2, wA2);

    if (ws_size >= need_b16) {
        // --- coalesced channels-last gather path ---
        const bool f32ok = (ws_size >= need_f32);
        float* flow_s = (float*)(wsb + off_after_xin);
        char* region  = wsb + off_after_xin + FLOW_B;
        // region timeline: img_row (lkw) -> featT (transpose+warp) -> t1cl (convs)
        float* img_row = (float*)region;
        void*  featT   = (void*)region;
        short* t1cl    = (short*)region;

        hipLaunchKernelGGL(lkw_row_kernel, dim3((n_img + 255) / 256), dim3(256), 0, stream,
                           img, flow, kp, img_row);
        hipLaunchKernelGGL(lkw_col_kernel, dim3((n_img + 255) / 256), dim3(256), 0, stream,
                           img_row, kp, out1);
        hipLaunchKernelGGL(downsample2x_kernel, dim3((NB * 2 * HWF + 255) / 256), dim3(256), 0, stream,
                           flow, flow_s, NB * 2, 0.5f);
        hipLaunchKernelGGL(imgdown_cl_kernel, dim3((NB * HWF + 255) / 256), dim3(256), 0, stream,
                           out1, xin);
        if (f32ok) {
            hipLaunchKernelGGL((feat_cl_kernel<0>), dim3(NB * (HWF / 64)), dim3(256), 0, stream,
                               feat, featT);
            hipLaunchKernelGGL((warp_feat_cl2_kernel<0>), dim3(NB * HWF * 8 / 256), dim3(256), 0, stream,
                               featT, flow_s, out0, xin);
        } else {
            hipLaunchKernelGGL((feat_cl_kernel<1>), dim3(NB * (HWF / 64)), dim3(256), 0, stream,
                               feat, featT);
            hipLaunchKernelGGL((warp_feat_cl2_kernel<1>), dim3(NB * HWF * 8 / 256), dim3(256), 0, stream,
                               featT, flow_s, out0, xin);
        }
        hipLaunchKernelGGL((conv_mfma2_kernel<1>), dim3(NB * FH * 2), dim3(256), 0, stream,
                           xin, wA1, b1, t1cl, (float*)nullptr);
        hipLaunchKernelGGL((conv_mfma2_kernel<2>), dim3(NB * FH * 2), dim3(256), 0, stream,
                           t1cl, wA2, b2, (short*)nullptr, out0);
    } else {
        // --- fallback (workspace too small for featT) ---
        char* region = wsb + off_after_xin;
        short* t1cl    = (short*)region;
        float* img_row = (float*)region;
        float* flow_s  = (float*)(region + 16777216);

        hipLaunchKernelGGL(lkw_row_kernel, dim3((n_img + 255) / 256), dim3(256), 0, stream,
                           img, flow, kp, img_row);
        hipLaunchKernelGGL(lkw_col_kernel, dim3((n_img + 255) / 256), dim3(256), 0, stream,
                           img_row, kp, out1);
        hipLaunchKernelGGL(downsample2x_kernel, dim3((NB * 2 * HWF + 255) / 256), dim3(256), 0, stream,
                           flow, flow_s, NB * 2, 0.5f);
        hipLaunchKernelGGL(imgdown_cl_kernel, dim3((NB * HWF + 255) / 256), dim3(256), 0, stream,
                           out1, xin);
        hipLaunchKernelGGL(warp_feat_cl_kernel, dim3(NB * HWF * 8 / 256), dim3(256), 0, stream,
                           feat, flow_s, out0, xin);
        hipLaunchKernelGGL((conv_mfma2_kernel<1>), dim3(NB * FH * 2), dim3(256), 0, stream,
                           xin, wA1, b1, t1cl, (float*)nullptr);
        hipLaunchKernelGGL((conv_mfma2_kernel<2>), dim3(NB * FH * 2), dim3(256), 0, stream,
                           t1cl, wA2, b2, (short*)nullptr, out0);
    }
}

// Round 3
// 729.237 us; speedup vs baseline: 1.0718x; 1.0718x over previous
//
#include <hip/hip_runtime.h>

#define NB 4
#define IH 512
#define IW 512
#define FH 256
#define FW 256
#define CF 96
#define C1 99
#define HWI (IH*IW)     /* 262144 */
#define HWF (FH*FW)     /* 65536  */
#define LDK 40          /* padded K stride (shorts) in LDS: 80B */

typedef short s8v __attribute__((ext_vector_type(8)));
typedef short s4v __attribute__((ext_vector_type(4)));
typedef float f4v __attribute__((ext_vector_type(4)));
typedef float f2v __attribute__((ext_vector_type(2), aligned(4)));  /* 4B-aligned pair load */

static __device__ __forceinline__ float sigmoidf_(float x) {
    return 1.0f / (1.0f + __expf(-x));
}
static __device__ __forceinline__ unsigned short f2bf(float f) {
    unsigned int u = __float_as_uint(f);
    unsigned int r = (u + 0x7fffu + ((u >> 16) & 1u)) >> 16;
    return (unsigned short)r;
}
static __device__ __forceinline__ float bf2f(short s) {
    unsigned int u = ((unsigned int)(unsigned short)s) << 16;
    return __uint_as_float(u);
}

// ---------------------------------------------------------------------------
// Pass 1 of local_kernel_warp (validated R1)
// ---------------------------------------------------------------------------
__global__ __launch_bounds__(256)
void lkw_row_kernel(const float* __restrict__ img,
                    const float* __restrict__ flow,
                    const float* __restrict__ kp,
                    float* __restrict__ img_row) {
    int idx = blockIdx.x * blockDim.x + threadIdx.x;
    if (idx >= NB * HWI) return;
    int w = idx & (IW - 1);
    int h = (idx >> 9) & (IH - 1);
    int b = idx >> 18;

    const float* kpb = kp + (size_t)b * 11 * HWI + h * IW + w;
    float p[5];
    float m = -1e30f;
    #pragma unroll
    for (int k = 0; k < 5; k++) { p[k] = kpb[k * HWI]; m = fmaxf(m, p[k]); }
    float s = 0.f;
    #pragma unroll
    for (int k = 0; k < 5; k++) { p[k] = __expf(p[k] - m); s += p[k]; }
    float invs = 1.f / s;
    float a = sigmoidf_(kpb[10 * HWI]) + 0.5f;
    float inva = 1.f / a;

    float fx = flow[((size_t)b * 2 + 0) * HWI + h * IW + w];
    float fy = flow[((size_t)b * 2 + 1) * HWI + h * IW + w];

    float y = (float)h + 0.5f * fy;
    y = fminf(fmaxf(y, 0.f), (float)(IH - 1));
    float y0f = floorf(y);
    int y0 = (int)y0f;
    int y1 = min(y0 + 1, IH - 1);
    float wy = y - y0f;

    float xbase = (float)w + 0.5f * fx;
    const float sc = (float)(IW - 1) / (float)IW;

    const float* imb = img + (size_t)b * 3 * HWI;
    float acc0 = 0.f, acc1 = 0.f, acc2 = 0.f;
    #pragma unroll
    for (int k = 0; k < 5; k++) {
        float x = xbase + (float)(k - 2) * inva * sc;
        x = fminf(fmaxf(x, 0.f), (float)(IW - 1));
        float x0f = floorf(x);
        int x0 = (int)x0f;
        int x1 = min(x0 + 1, IW - 1);
        float wx = x - x0f;
        float wk = p[k] * invs;
        float w00 = (1.f - wx) * (1.f - wy) * wk;
        float w01 = wx * (1.f - wy) * wk;
        float w10 = (1.f - wx) * wy * wk;
        float w11 = wx * wy * wk;
        int i00 = y0 * IW + x0, i01 = y0 * IW + x1;
        int i10 = y1 * IW + x0, i11 = y1 * IW + x1;
        acc0 += w00 * imb[i00] + w01 * imb[i01] + w10 * imb[i10] + w11 * imb[i11];
        acc1 += w00 * imb[HWI + i00] + w01 * imb[HWI + i01] + w10 * imb[HWI + i10] + w11 * imb[HWI + i11];
        acc2 += w00 * imb[2 * HWI + i00] + w01 * imb[2 * HWI + i01] + w10 * imb[2 * HWI + i10] + w11 * imb[2 * HWI + i11];
    }
    img_row[(size_t)b * 3 * HWI + h * IW + w] = acc0;
    img_row[(size_t)b * 3 * HWI + HWI + h * IW + w] = acc1;
    img_row[(size_t)b * 3 * HWI + 2 * HWI + h * IW + w] = acc2;
}

// ---------------------------------------------------------------------------
// Pass 2 (validated R1)
// ---------------------------------------------------------------------------
__global__ __launch_bounds__(256)
void lkw_col_kernel(const float* __restrict__ img_row,
                    const float* __restrict__ kp,
                    float* __restrict__ out1) {
    int idx = blockIdx.x * blockDim.x + threadIdx.x;
    if (idx >= NB * HWI) return;
    int w = idx & (IW - 1);
    int h = (idx >> 9) & (IH - 1);
    int b = idx >> 18;

    const float* kpb = kp + (size_t)b * 11 * HWI + h * IW + w;
    float p[5];
    float m = -1e30f;
    #pragma unroll
    for (int k = 0; k < 5; k++) { p[k] = kpb[(5 + k) * HWI]; m = fmaxf(m, p[k]); }
    float s = 0.f;
    #pragma unroll
    for (int k = 0; k < 5; k++) { p[k] = __expf(p[k] - m); s += p[k]; }
    float invs = 1.f / s;
    float a = sigmoidf_(kpb[10 * HWI]) + 0.5f;

    const float sc = (float)(IH - 1) / (float)IH;
    const float* irb = img_row + (size_t)b * 3 * HWI;
    float acc0 = 0.f, acc1 = 0.f, acc2 = 0.f;
    #pragma unroll
    for (int k = 0; k < 5; k++) {
        float y = (float)h + (float)(k - 2) * a * sc;
        y = fminf(fmaxf(y, 0.f), (float)(IH - 1));
        float y0f = floorf(y);
        int y0 = (int)y0f;
        int y1 = min(y0 + 1, IH - 1);
        float wy = y - y0f;
        float wk = p[k] * invs;
        float w0 = (1.f - wy) * wk, w1 = wy * wk;
        int i0 = y0 * IW + w, i1 = y1 * IW + w;
        acc0 += w0 * irb[i0] + w1 * irb[i1];
        acc1 += w0 * irb[HWI + i0] + w1 * irb[HWI + i1];
        acc2 += w0 * irb[2 * HWI + i0] + w1 * irb[2 * HWI + i1];
    }
    out1[(size_t)b * 3 * HWI + h * IW + w] = acc0;
    out1[(size_t)b * 3 * HWI + HWI + h * IW + w] = acc1;
    out1[(size_t)b * 3 * HWI + 2 * HWI + h * IW + w] = acc2;
}

// ---------------------------------------------------------------------------
// antialiased 2x downsample taps (validated R1)
// ---------------------------------------------------------------------------
static __device__ __forceinline__ void ds_taps(int i, int n_in, int t[4], float wt[4]) {
    int n_out = n_in >> 1;
    if (i == 0) {
        t[0] = 0; t[1] = 0; t[2] = 1; t[3] = 2;
        wt[0] = 0.f; wt[1] = 3.f / 7.f; wt[2] = 3.f / 7.f; wt[3] = 1.f / 7.f;
    } else if (i == n_out - 1) {
        t[0] = n_in - 3; t[1] = n_in - 2; t[2] = n_in - 1; t[3] = n_in - 1;
        wt[0] = 1.f / 7.f; wt[1] = 3.f / 7.f; wt[2] = 3.f / 7.f; wt[3] = 0.f;
    } else {
        t[0] = 2 * i - 1; t[1] = 2 * i; t[2] = 2 * i + 1; t[3] = 2 * i + 2;
        wt[0] = 0.125f; wt[1] = 0.375f; wt[2] = 0.375f; wt[3] = 0.125f;
    }
}

__global__ __launch_bounds__(256)
void downsample2x_kernel(const float* __restrict__ src, float* __restrict__ dst,
                         int BC, float mul) {
    int idx = blockIdx.x * blockDim.x + threadIdx.x;
    if (idx >= BC * HWF) return;
    int j = idx & (FW - 1);
    int i = (idx >> 8) & (FH - 1);
    int bc = idx >> 16;

    int tx[4], ty[4];
    float wx[4], wy[4];
    ds_taps(j, IW, tx, wx);
    ds_taps(i, IH, ty, wy);
    const float* s = src + (size_t)bc * HWI;
    float acc = 0.f;
    #pragma unroll
    for (int a = 0; a < 4; a++) {
        if (wy[a] == 0.f) continue;
        const float* rp = s + (size_t)ty[a] * IW;
        float row = wx[0] * rp[tx[0]] + wx[1] * rp[tx[1]] + wx[2] * rp[tx[2]] + wx[3] * rp[tx[3]];
        acc += wy[a] * row;
    }
    dst[idx] = acc * mul;
}

// ---------------------------------------------------------------------------
// img downsample -> channels-last bf16 xin slots [96..128)
// ---------------------------------------------------------------------------
__global__ __launch_bounds__(256)
void imgdown_cl_kernel(const float* __restrict__ out1, short* __restrict__ xin) {
    int idx = blockIdx.x * blockDim.x + threadIdx.x;
    if (idx >= NB * HWF) return;
    int j = idx & (FW - 1);
    int i = (idx >> 8) & (FH - 1);
    int b = idx >> 16;

    int tx[4], ty[4];
    float wx[4], wy[4];
    ds_taps(j, IW, tx, wx);
    ds_taps(i, IH, ty, wy);
    const float* s = out1 + (size_t)b * 3 * HWI;
    float acc[3] = {0.f, 0.f, 0.f};
    #pragma unroll
    for (int a = 0; a < 4; a++) {
        if (wy[a] == 0.f) continue;
        #pragma unroll
        for (int c = 0; c < 3; c++) {
            const float* rp = s + (size_t)c * HWI + (size_t)ty[a] * IW;
            float row = wx[0] * rp[tx[0]] + wx[1] * rp[tx[1]] + wx[2] * rp[tx[2]] + wx[3] * rp[tx[3]];
            acc[c] += wy[a] * row;
        }
    }
    short* dst = xin + ((size_t)(b * FH + i) * FW + j) * 128 + 96;
    s8v g0 = { (short)f2bf(acc[0]), (short)f2bf(acc[1]), (short)f2bf(acc[2]), 0, 0, 0, 0, 0 };
    s8v z  = { 0, 0, 0, 0, 0, 0, 0, 0 };
    *(s8v*)(dst)      = g0;
    *(s8v*)(dst + 8)  = z;
    *(s8v*)(dst + 16) = z;
    *(s8v*)(dst + 24) = z;
}

// ---------------------------------------------------------------------------
// feat [B][96][H][W] fp32 -> featT [B][H][W][96] channels-last (validated R1)
// ---------------------------------------------------------------------------
template <int BF>
__global__ __launch_bounds__(256)
void feat_cl_kernel(const float* __restrict__ feat, void* __restrict__ featT) {
    __shared__ float tile[64 * 97];
    int blk = blockIdx.x;                 // NB * (HWF/64) = 4096
    int b = blk >> 10;                    // HWF/64 = 1024
    int p0 = (blk & 1023) << 6;
    int t = threadIdx.x;
    {
        int px = t & 63, cq = t >> 6;     // cq: 4 groups of 24 channels
        const float* src = feat + (size_t)b * CF * HWF + p0 + px;
        #pragma unroll
        for (int k = 0; k < 24; k++) {
            int c = cq * 24 + k;
            tile[px * 97 + c] = src[(size_t)c * HWF];
        }
    }
    __syncthreads();
    int pxo = t >> 2, co = (t & 3) * 24;  // 4 threads per pixel, 24 ch each
    const float* trow = &tile[pxo * 97 + co];
    size_t obase = ((size_t)(b * HWF) + p0 + pxo) * 96 + co;
    if (BF) {
        short* dst = (short*)featT + obase;
        #pragma unroll
        for (int q = 0; q < 3; q++) {
            s8v pk;
            #pragma unroll
            for (int e = 0; e < 8; e++) pk[e] = (short)f2bf(trow[q * 8 + e]);
            *(s8v*)(dst + q * 8) = pk;
        }
    } else {
        float* dst = (float*)featT + obase;
        #pragma unroll
        for (int q = 0; q < 6; q++) {
            f4v vv = { trow[q * 4 + 0], trow[q * 4 + 1], trow[q * 4 + 2], trow[q * 4 + 3] };
            *(f4v*)(dst + q * 4) = vv;
        }
    }
}

// ---------------------------------------------------------------------------
// backward_warp(features) v3 over channels-last featT (validated R1)
// ---------------------------------------------------------------------------
template <int BF>
__global__ __launch_bounds__(256)
void warp_feat_cl2_kernel(const void* __restrict__ featT,
                          const float* __restrict__ flow_s,
                          float* __restrict__ wfeat,
                          short* __restrict__ xin) {
    int t = blockIdx.x * 256 + threadIdx.x;   // [0, NB*HWF*8)
    int g = t & 7;                            // channel group: 12 channels
    int pix = t >> 3;                         // [0, NB*HWF)
    int j = pix & (FW - 1);
    int i = (pix >> 8) & (FH - 1);
    int b = pix >> 16;

    float fx = flow_s[((size_t)b * 2 + 0) * HWF + i * FW + j];
    float fy = flow_s[((size_t)b * 2 + 1) * HWF + i * FW + j];
    float u = (float)j + 0.5f * fx;
    float v = (float)i + 0.5f * fy;
    bool valid = (u >= 0.f) && (u <= (float)(FW - 1)) && (v >= 0.f) && (v <= (float)(FH - 1));
    float x = fminf(fmaxf(u, 0.f), (float)(FW - 1));
    float y = fminf(fmaxf(v, 0.f), (float)(FH - 1));
    int x0 = min((int)x, FW - 2);
    int y0 = min((int)y, FH - 2);
    float wxf = x - (float)x0, wyf = y - (float)y0;
    float w00 = (1.f - wxf) * (1.f - wyf), w01 = wxf * (1.f - wyf);
    float w10 = (1.f - wxf) * wyf, w11 = wxf * wyf;
    if (!valid) { w00 = w01 = w10 = w11 = 0.f; }

    size_t base = ((size_t)(b * HWF) + (size_t)y0 * FW + x0) * 96 + g * 12;
    float vals[12];
    if (BF) {
        const short* fp = (const short*)featT + base;
        #pragma unroll
        for (int q = 0; q < 3; q++) {
            s4v a0 = *(const s4v*)(fp + q * 4);
            s4v a1 = *(const s4v*)(fp + 96 + q * 4);
            s4v a2 = *(const s4v*)(fp + 96 * FW + q * 4);
            s4v a3 = *(const s4v*)(fp + 96 * FW + 96 + q * 4);
            #pragma unroll
            for (int e = 0; e < 4; e++)
                vals[q * 4 + e] = w00 * bf2f(a0[e]) + w01 * bf2f(a1[e])
                                + w10 * bf2f(a2[e]) + w11 * bf2f(a3[e]);
        }
    } else {
        const float* fp = (const float*)featT + base;
        #pragma unroll
        for (int q = 0; q < 3; q++) {
            f4v a0 = *(const f4v*)(fp + q * 4);
            f4v a1 = *(const f4v*)(fp + 96 + q * 4);
            f4v a2 = *(const f4v*)(fp + 96 * FW + q * 4);
            f4v a3 = *(const f4v*)(fp + 96 * FW + 96 + q * 4);
            #pragma unroll
            for (int e = 0; e < 4; e++)
                vals[q * 4 + e] = w00 * a0[e] + w01 * a1[e] + w10 * a2[e] + w11 * a3[e];
        }
    }

    float* ob = wfeat + ((size_t)b * CF + g * 12) * HWF + (size_t)i * FW + j;
    #pragma unroll
    for (int k = 0; k < 12; k++) ob[(size_t)k * HWF] = vals[k];

    short* xr = xin + (size_t)pix * 128 + g * 12;   // 24B per thread, 8B-aligned
    #pragma unroll
    for (int q2 = 0; q2 < 3; q2++) {
        s4v pk = { (short)f2bf(vals[q2 * 4 + 0]), (short)f2bf(vals[q2 * 4 + 1]),
                   (short)f2bf(vals[q2 * 4 + 2]), (short)f2bf(vals[q2 * 4 + 3]) };
        *(s4v*)(xr + q2 * 4) = pk;
    }
}

// ---------------------------------------------------------------------------
// backward_warp(features) v2 (validated R3) — kept as workspace-size fallback
// ---------------------------------------------------------------------------
__global__ __launch_bounds__(256)
void warp_feat_cl_kernel(const float* __restrict__ feat,
                         const float* __restrict__ flow_s,
                         float* __restrict__ wfeat,
                         short* __restrict__ xin) {
    int t = blockIdx.x * 256 + threadIdx.x;   // [0, NB*HWF*8)
    int g = t & 7;                            // channel group: 12 channels
    int pix = t >> 3;                         // [0, NB*HWF)
    int j = pix & (FW - 1);
    int i = (pix >> 8) & (FH - 1);
    int b = pix >> 16;

    float fx = flow_s[((size_t)b * 2 + 0) * HWF + i * FW + j];
    float fy = flow_s[((size_t)b * 2 + 1) * HWF + i * FW + j];
    float u = (float)j + 0.5f * fx;
    float v = (float)i + 0.5f * fy;
    bool valid = (u >= 0.f) && (u <= (float)(FW - 1)) && (v >= 0.f) && (v <= (float)(FH - 1));
    float x = fminf(fmaxf(u, 0.f), (float)(FW - 1));
    float y = fminf(fmaxf(v, 0.f), (float)(FH - 1));
    int x0 = min((int)x, FW - 2);
    int y0 = min((int)y, FH - 2);
    float wxf = x - (float)x0, wyf = y - (float)y0;
    float w00 = (1.f - wxf) * (1.f - wyf), w01 = wxf * (1.f - wyf);
    float w10 = (1.f - wxf) * wyf, w11 = wxf * wyf;
    if (!valid) { w00 = w01 = w10 = w11 = 0.f; }

    const float* fb = feat + ((size_t)b * CF + g * 12) * HWF + (size_t)y0 * FW + x0;
    float vals[12];
    #pragma unroll
    for (int k = 0; k < 12; k++) {
        const float* p = fb + (size_t)k * HWF;
        f2v r0 = *(const f2v*)p;
        f2v r1 = *(const f2v*)(p + FW);
        vals[k] = w00 * r0.x + w01 * r0.y + w10 * r1.x + w11 * r1.y;
    }

    float* ob = wfeat + ((size_t)b * CF + g * 12) * HWF + (size_t)i * FW + j;
    #pragma unroll
    for (int k = 0; k < 12; k++) ob[(size_t)k * HWF] = vals[k];

    short* xr = xin + (size_t)pix * 128 + g * 12;   // 24B per thread, 8B-aligned
    #pragma unroll
    for (int q2 = 0; q2 < 3; q2++) {
        s4v pk = { (short)f2bf(vals[q2 * 4 + 0]), (short)f2bf(vals[q2 * 4 + 1]),
                   (short)f2bf(vals[q2 * 4 + 2]), (short)f2bf(vals[q2 * 4 + 3]) };
        *(s4v*)(xr + q2 * 4) = pk;
    }
}

// ---------------------------------------------------------------------------
// Weight repack R2: w[co][ci][3][3] fp32 -> wA[kc][dy][dx][co][32ci] bf16.
// Per conv step (kc,dy) the A tile (3dx*96co*32ci = 18.4KB) is contiguous
// -> fully coalesced staging.
// ---------------------------------------------------------------------------
__global__ __launch_bounds__(256)
void cvt_w1_kernel(const float* __restrict__ w1, short* __restrict__ wA1) {
    int i = blockIdx.x * 256 + threadIdx.x;
    if (i >= 4 * 3 * 3 * 96 * 32) return;
    int cl = i & 31;
    int co = (i >> 5) % 96;
    int rest = i / 3072;
    int dx = rest % 3;
    int dy = (rest / 3) % 3;
    int kc = rest / 9;
    int ci = kc * 32 + cl;
    float v = (ci < C1) ? w1[((size_t)co * C1 + ci) * 9 + dy * 3 + dx] : 0.f;
    wA1[i] = (short)f2bf(v);
}
__global__ __launch_bounds__(256)
void cvt_w2_kernel(const float* __restrict__ w2, short* __restrict__ wA2) {
    int i = blockIdx.x * 256 + threadIdx.x;
    if (i >= 3 * 3 * 3 * 96 * 32) return;
    int cl = i & 31;
    int co = (i >> 5) % 96;
    int rest = i / 3072;
    int dx = rest % 3;
    int dy = (rest / 3) % 3;
    int kc = rest / 9;
    wA2[i] = (short)f2bf(w2[((size_t)co * CF + kc * 32 + cl) * 9 + dy * 3 + dx]);
}

// ---------------------------------------------------------------------------
// MFMA implicit-GEMM 3x3 conv v3 (= v2 schedule, spill-free regalloc).
// launch_bounds(256,2): VGPR cap 256 -> acc(48)+stage(32)+addr fit, no
// scratch. Staging rebalanced: every thread holds exactly TWO 64B row
// buffers (pa: A row tid; pc: A row 256+tid for tid<32, else B halo pixel
// tid-32 for tid<162).
// ---------------------------------------------------------------------------
template <int PASS>
__global__ __launch_bounds__(256, 2)
void conv_mfma3_kernel(const short* __restrict__ X,    // [b][h][w][KSTR] bf16
                      const short* __restrict__ W,     // [KC][3dy][3dx][96co][32ci] bf16
                      const float* __restrict__ bias,
                      short* __restrict__ t1out,
                      float* __restrict__ out0) {
    constexpr int KSTR = (PASS == 1) ? 128 : 96;
    constexpr int KC = KSTR / 32;
    __shared__ short Als[288 * LDK];   // [dx*96+co][32ci]
    __shared__ short Bls[132 * LDK];   // [halo pixel 0..129][32ci]

    const int bx = blockIdx.x;
    const int w0 = (bx & 1) * 128;
    const int h  = (bx >> 1) & (FH - 1);
    const int b  = bx >> 9;

    const int tid = threadIdx.x;
    const int lane = tid & 63;
    const int wv = tid >> 6;
    const int ln = lane & 15;
    const int q  = lane >> 4;

    f4v acc[6][2];
    #pragma unroll
    for (int mt = 0; mt < 6; mt++)
        #pragma unroll
        for (int nt = 0; nt < 2; nt++)
            acc[mt][nt] = (f4v){0.f, 0.f, 0.f, 0.f};

    const short* Xb = X + (size_t)(b * FH) * FW * KSTR;
    const int wp = w0 - 33 + tid;                      // halo pixel (tid-32 slot)
    const bool isb = (tid >= 32) && (tid < 162);

    float4 pa[4], pc[4];

    auto load_step = [&](int stepn, int kcn, int dyn) {
        const short* srcA = W + ((size_t)stepn * 288 + tid) * 32;
        pa[0] = *(const float4*)(srcA);
        pa[1] = *(const float4*)(srcA + 8);
        pa[2] = *(const float4*)(srcA + 16);
        pa[3] = *(const float4*)(srcA + 24);
        if (tid < 32) {
            const short* srcC = srcA + 256 * 32;
            pc[0] = *(const float4*)(srcC);
            pc[1] = *(const float4*)(srcC + 8);
            pc[2] = *(const float4*)(srcC + 16);
            pc[3] = *(const float4*)(srcC + 24);
        } else if (isb) {
            int hy = h + dyn - 1;
            if (hy >= 0 && hy < FH && wp >= 0 && wp < FW) {
                const short* srcB = Xb + ((size_t)hy * FW + wp) * KSTR + kcn * 32;
                pc[0] = *(const float4*)(srcB);
                pc[1] = *(const float4*)(srcB + 8);
                pc[2] = *(const float4*)(srcB + 16);
                pc[3] = *(const float4*)(srcB + 24);
            } else {
                pc[0] = pc[1] = pc[2] = pc[3] = (float4){0.f, 0.f, 0.f, 0.f};
            }
        }
    };

    load_step(0, 0, 0);

    int step = 0;
    for (int kc = 0; kc < KC; ++kc) {
        for (int dy = 0; dy < 3; ++dy, ++step) {
            __syncthreads();                         // prev compute's LDS reads done
            {
                short* dA = Als + tid * LDK;
                *(float4*)(dA)      = pa[0];
                *(float4*)(dA + 8)  = pa[1];
                *(float4*)(dA + 16) = pa[2];
                *(float4*)(dA + 24) = pa[3];
                if (tid < 162) {
                    short* d2 = (tid < 32) ? (Als + (256 + tid) * LDK)
                                           : (Bls + (tid - 32) * LDK);
                    *(float4*)(d2)      = pc[0];
                    *(float4*)(d2 + 8)  = pc[1];
                    *(float4*)(d2 + 16) = pc[2];
                    *(float4*)(d2 + 24) = pc[3];
                }
            }
            __syncthreads();
            {   // issue next step's global loads; latency hides under MFMAs
                int ndy = dy + 1, nkc = kc;
                if (ndy == 3) { ndy = 0; nkc++; }
                if (nkc < KC) load_step(step + 1, nkc, ndy);
            }
            #pragma unroll
            for (int dx = 0; dx < 3; ++dx) {
                s8v bfr0 = *(const s8v*)(Bls + (wv * 32 + ln + dx) * LDK + q * 8);
                s8v bfr1 = *(const s8v*)(Bls + (wv * 32 + 16 + ln + dx) * LDK + q * 8);
                #pragma unroll
                for (int mt = 0; mt < 6; ++mt) {
                    s8v afr = *(const s8v*)(Als + (dx * 96 + mt * 16 + ln) * LDK + q * 8);
                    acc[mt][0] = __builtin_amdgcn_mfma_f32_16x16x32_bf16(afr, bfr0, acc[mt][0], 0, 0, 0);
                    acc[mt][1] = __builtin_amdgcn_mfma_f32_16x16x32_bf16(afr, bfr1, acc[mt][1], 0, 0, 0);
                }
            }
        }
    }

    if (PASS == 1) {
        const size_t rowbase = (size_t)(b * FH + h) * FW;
        #pragma unroll
        for (int nt = 0; nt < 2; ++nt) {
            int pos = w0 + wv * 32 + nt * 16 + ln;
            short* dst = t1out + (rowbase + pos) * CF;
            #pragma unroll
            for (int mt = 0; mt < 6; ++mt) {
                int co0 = mt * 16 + q * 4;
                s4v pk;
                #pragma unroll
                for (int r = 0; r < 4; ++r) {
                    float v = acc[mt][nt][r] + bias[co0 + r];
                    pk[r] = (short)f2bf(fmaxf(v, 0.f));
                }
                *(s4v*)(dst + co0) = pk;
            }
        }
    } else {
        #pragma unroll
        for (int nt = 0; nt < 2; ++nt) {
            int pos = w0 + wv * 32 + nt * 16 + ln;
            #pragma unroll
            for (int mt = 0; mt < 6; ++mt) {
                int co0 = mt * 16 + q * 4;
                #pragma unroll
                for (int r = 0; r < 4; ++r) {
                    size_t o = (size_t)(b * CF + co0 + r) * HWF + (size_t)h * FW + pos;
                    out0[o] += acc[mt][nt][r] + bias[co0 + r];
                }
            }
        }
    }
}

extern "C" void kernel_launch(void* const* d_in, const int* in_sizes, int n_in,
                              void* d_out, int out_size, void* d_ws, size_t ws_size,
                              hipStream_t stream) {
    const float* img  = (const float*)d_in[0];
    const float* feat = (const float*)d_in[1];
    const float* flow = (const float*)d_in[2];
    const float* kp   = (const float*)d_in[3];
    const float* w1   = (const float*)d_in[4];
    const float* b1   = (const float*)d_in[5];
    const float* w2   = (const float*)d_in[6];
    const float* b2   = (const float*)d_in[7];

    float* out0 = (float*)d_out;                       // [B,96,256,256] fp32
    float* out1 = out0 + (size_t)NB * CF * HWF;        // [B,3,512,512]  fp32

    char* wsb = (char*)d_ws;
    short* wA1 = (short*)wsb;                                   //   221,184 B
    short* wA2 = (short*)(wsb + 221184);                        //   165,888 B
    short* xin = (short*)(wsb + 387072);                        // 67,108,864 B [b][h][w][128]
    const size_t off_after_xin = 387072 + 67108864;             // 67,495,936

    const size_t FEATT_F32 = (size_t)NB * HWF * 96 * 4;         // 100,663,296
    const size_t FEATT_BF16 = (size_t)NB * HWF * 96 * 2;        //  50,331,648
    const size_t FLOW_B = 2097152;
    const size_t need_f32 = off_after_xin + FLOW_B + FEATT_F32; // 170,256,384
    const size_t need_b16 = off_after_xin + FLOW_B + FEATT_BF16;// 119,924,736

    int n_img = NB * HWI;
    hipLaunchKernelGGL(cvt_w1_kernel, dim3((9 * 96 * 128 + 255) / 256), dim3(256), 0, stream, w1, wA1);
    hipLaunchKernelGGL(cvt_w2_kernel, dim3((9 * 96 * 96 + 255) / 256), dim3(256), 0, stream, w2, wA2);

    if (ws_size >= need_b16) {
        // --- coalesced channels-last gather path ---
        const bool f32ok = (ws_size >= need_f32);
        float* flow_s = (float*)(wsb + off_after_xin);
        char* region  = wsb + off_after_xin + FLOW_B;
        // region timeline: img_row (lkw) -> featT (transpose+warp) -> t1cl (convs)
        float* img_row = (float*)region;
        void*  featT   = (void*)region;
        short* t1cl    = (short*)region;

        hipLaunchKernelGGL(lkw_row_kernel, dim3((n_img + 255) / 256), dim3(256), 0, stream,
                           img, flow, kp, img_row);
        hipLaunchKernelGGL(lkw_col_kernel, dim3((n_img + 255) / 256), dim3(256), 0, stream,
                           img_row, kp, out1);
        hipLaunchKernelGGL(downsample2x_kernel, dim3((NB * 2 * HWF + 255) / 256), dim3(256), 0, stream,
                           flow, flow_s, NB * 2, 0.5f);
        hipLaunchKernelGGL(imgdown_cl_kernel, dim3((NB * HWF + 255) / 256), dim3(256), 0, stream,
                           out1, xin);
        if (f32ok) {
            hipLaunchKernelGGL((feat_cl_kernel<0>), dim3(NB * (HWF / 64)), dim3(256), 0, stream,
                               feat, featT);
            hipLaunchKernelGGL((warp_feat_cl2_kernel<0>), dim3(NB * HWF * 8 / 256), dim3(256), 0, stream,
                               featT, flow_s, out0, xin);
        } else {
            hipLaunchKernelGGL((feat_cl_kernel<1>), dim3(NB * (HWF / 64)), dim3(256), 0, stream,
                               feat, featT);
            hipLaunchKernelGGL((warp_feat_cl2_kernel<1>), dim3(NB * HWF * 8 / 256), dim3(256), 0, stream,
                               featT, flow_s, out0, xin);
        }
        hipLaunchKernelGGL((conv_mfma3_kernel<1>), dim3(NB * FH * 2), dim3(256), 0, stream,
                           xin, wA1, b1, t1cl, (float*)nullptr);
        hipLaunchKernelGGL((conv_mfma3_kernel<2>), dim3(NB * FH * 2), dim3(256), 0, stream,
                           t1cl, wA2, b2, (short*)nullptr, out0);
    } else {
        // --- fallback (workspace too small for featT) ---
        char* region = wsb + off_after_xin;
        short* t1cl    = (short*)region;
        float* img_row = (float*)region;
        float* flow_s  = (float*)(region + 16777216);

        hipLaunchKernelGGL(lkw_row_kernel, dim3((n_img + 255) / 256), dim3(256), 0, stream,
                           img, flow, kp, img_row);
        hipLaunchKernelGGL(lkw_col_kernel, dim3((n_img + 255) / 256), dim3(256), 0, stream,
                           img_row, kp, out1);
        hipLaunchKernelGGL(downsample2x_kernel, dim3((NB * 2 * HWF + 255) / 256), dim3(256), 0, stream,
                           flow, flow_s, NB * 2, 0.5f);
        hipLaunchKernelGGL(imgdown_cl_kernel, dim3((NB * HWF + 255) / 256), dim3(256), 0, stream,
                           out1, xin);
        hipLaunchKernelGGL(warp_feat_cl_kernel, dim3(NB * HWF * 8 / 256), dim3(256), 0, stream,
                           feat, flow_s, out0, xin);
        hipLaunchKernelGGL((conv_mfma3_kernel<1>), dim3(NB * FH * 2), dim3(256), 0, stream,
                           xin, wA1, b1, t1cl, (float*)nullptr);
        hipLaunchKernelGGL((conv_mfma3_kernel<2>), dim3(NB * FH * 2), dim3(256), 0, stream,
                           t1cl, wA2, b2, (short*)nullptr, out0);
    }
}

// Round 4
// 606.053 us; speedup vs baseline: 1.2897x; 1.2033x over previous
//
#include <hip/hip_runtime.h>

#define NB 4
#define IH 512
#define IW 512
#define FH 256
#define FW 256
#define CF 96
#define C1 99
#define HWI (IH*IW)     /* 262144 */
#define HWF (FH*FW)     /* 65536  */

typedef short s8v __attribute__((ext_vector_type(8)));
typedef short s4v __attribute__((ext_vector_type(4)));
typedef float f4v __attribute__((ext_vector_type(4)));
typedef float f2v __attribute__((ext_vector_type(2), aligned(4)));  /* 4B-aligned pair load */

static __device__ __forceinline__ float sigmoidf_(float x) {
    return 1.0f / (1.0f + __expf(-x));
}
static __device__ __forceinline__ unsigned short f2bf(float f) {
    unsigned int u = __float_as_uint(f);
    unsigned int r = (u + 0x7fffu + ((u >> 16) & 1u)) >> 16;
    return (unsigned short)r;
}
static __device__ __forceinline__ float bf2f(short s) {
    unsigned int u = ((unsigned int)(unsigned short)s) << 16;
    return __uint_as_float(u);
}
// async global->LDS DMA, 16B per lane; LDS dest = wave-uniform base + lane*16
static __device__ __forceinline__ void gl_lds16(const short* g, short* l) {
    __builtin_amdgcn_global_load_lds(
        (const __attribute__((address_space(1))) void*)g,
        (__attribute__((address_space(3))) void*)l, 16, 0, 0);
}

// ---------------------------------------------------------------------------
// Pass 1 of local_kernel_warp (validated R1)
// ---------------------------------------------------------------------------
__global__ __launch_bounds__(256)
void lkw_row_kernel(const float* __restrict__ img,
                    const float* __restrict__ flow,
                    const float* __restrict__ kp,
                    float* __restrict__ img_row) {
    int idx = blockIdx.x * blockDim.x + threadIdx.x;
    if (idx >= NB * HWI) return;
    int w = idx & (IW - 1);
    int h = (idx >> 9) & (IH - 1);
    int b = idx >> 18;

    const float* kpb = kp + (size_t)b * 11 * HWI + h * IW + w;
    float p[5];
    float m = -1e30f;
    #pragma unroll
    for (int k = 0; k < 5; k++) { p[k] = kpb[k * HWI]; m = fmaxf(m, p[k]); }
    float s = 0.f;
    #pragma unroll
    for (int k = 0; k < 5; k++) { p[k] = __expf(p[k] - m); s += p[k]; }
    float invs = 1.f / s;
    float a = sigmoidf_(kpb[10 * HWI]) + 0.5f;
    float inva = 1.f / a;

    float fx = flow[((size_t)b * 2 + 0) * HWI + h * IW + w];
    float fy = flow[((size_t)b * 2 + 1) * HWI + h * IW + w];

    float y = (float)h + 0.5f * fy;
    y = fminf(fmaxf(y, 0.f), (float)(IH - 1));
    float y0f = floorf(y);
    int y0 = (int)y0f;
    int y1 = min(y0 + 1, IH - 1);
    float wy = y - y0f;

    float xbase = (float)w + 0.5f * fx;
    const float sc = (float)(IW - 1) / (float)IW;

    const float* imb = img + (size_t)b * 3 * HWI;
    float acc0 = 0.f, acc1 = 0.f, acc2 = 0.f;
    #pragma unroll
    for (int k = 0; k < 5; k++) {
        float x = xbase + (float)(k - 2) * inva * sc;
        x = fminf(fmaxf(x, 0.f), (float)(IW - 1));
        float x0f = floorf(x);
        int x0 = (int)x0f;
        int x1 = min(x0 + 1, IW - 1);
        float wx = x - x0f;
        float wk = p[k] * invs;
        float w00 = (1.f - wx) * (1.f - wy) * wk;
        float w01 = wx * (1.f - wy) * wk;
        float w10 = (1.f - wx) * wy * wk;
        float w11 = wx * wy * wk;
        int i00 = y0 * IW + x0, i01 = y0 * IW + x1;
        int i10 = y1 * IW + x0, i11 = y1 * IW + x1;
        acc0 += w00 * imb[i00] + w01 * imb[i01] + w10 * imb[i10] + w11 * imb[i11];
        acc1 += w00 * imb[HWI + i00] + w01 * imb[HWI + i01] + w10 * imb[HWI + i10] + w11 * imb[HWI + i11];
        acc2 += w00 * imb[2 * HWI + i00] + w01 * imb[2 * HWI + i01] + w10 * imb[2 * HWI + i10] + w11 * imb[2 * HWI + i11];
    }
    img_row[(size_t)b * 3 * HWI + h * IW + w] = acc0;
    img_row[(size_t)b * 3 * HWI + HWI + h * IW + w] = acc1;
    img_row[(size_t)b * 3 * HWI + 2 * HWI + h * IW + w] = acc2;
}

// ---------------------------------------------------------------------------
// Pass 2 (validated R1)
// ---------------------------------------------------------------------------
__global__ __launch_bounds__(256)
void lkw_col_kernel(const float* __restrict__ img_row,
                    const float* __restrict__ kp,
                    float* __restrict__ out1) {
    int idx = blockIdx.x * blockDim.x + threadIdx.x;
    if (idx >= NB * HWI) return;
    int w = idx & (IW - 1);
    int h = (idx >> 9) & (IH - 1);
    int b = idx >> 18;

    const float* kpb = kp + (size_t)b * 11 * HWI + h * IW + w;
    float p[5];
    float m = -1e30f;
    #pragma unroll
    for (int k = 0; k < 5; k++) { p[k] = kpb[(5 + k) * HWI]; m = fmaxf(m, p[k]); }
    float s = 0.f;
    #pragma unroll
    for (int k = 0; k < 5; k++) { p[k] = __expf(p[k] - m); s += p[k]; }
    float invs = 1.f / s;
    float a = sigmoidf_(kpb[10 * HWI]) + 0.5f;

    const float sc = (float)(IH - 1) / (float)IH;
    const float* irb = img_row + (size_t)b * 3 * HWI;
    float acc0 = 0.f, acc1 = 0.f, acc2 = 0.f;
    #pragma unroll
    for (int k = 0; k < 5; k++) {
        float y = (float)h + (float)(k - 2) * a * sc;
        y = fminf(fmaxf(y, 0.f), (float)(IH - 1));
        float y0f = floorf(y);
        int y0 = (int)y0f;
        int y1 = min(y0 + 1, IH - 1);
        float wy = y - y0f;
        float wk = p[k] * invs;
        float w0 = (1.f - wy) * wk, w1 = wy * wk;
        int i0 = y0 * IW + w, i1 = y1 * IW + w;
        acc0 += w0 * irb[i0] + w1 * irb[i1];
        acc1 += w0 * irb[HWI + i0] + w1 * irb[HWI + i1];
        acc2 += w0 * irb[2 * HWI + i0] + w1 * irb[2 * HWI + i1];
    }
    out1[(size_t)b * 3 * HWI + h * IW + w] = acc0;
    out1[(size_t)b * 3 * HWI + HWI + h * IW + w] = acc1;
    out1[(size_t)b * 3 * HWI + 2 * HWI + h * IW + w] = acc2;
}

// ---------------------------------------------------------------------------
// antialiased 2x downsample taps (validated R1)
// ---------------------------------------------------------------------------
static __device__ __forceinline__ void ds_taps(int i, int n_in, int t[4], float wt[4]) {
    int n_out = n_in >> 1;
    if (i == 0) {
        t[0] = 0; t[1] = 0; t[2] = 1; t[3] = 2;
        wt[0] = 0.f; wt[1] = 3.f / 7.f; wt[2] = 3.f / 7.f; wt[3] = 1.f / 7.f;
    } else if (i == n_out - 1) {
        t[0] = n_in - 3; t[1] = n_in - 2; t[2] = n_in - 1; t[3] = n_in - 1;
        wt[0] = 1.f / 7.f; wt[1] = 3.f / 7.f; wt[2] = 3.f / 7.f; wt[3] = 0.f;
    } else {
        t[0] = 2 * i - 1; t[1] = 2 * i; t[2] = 2 * i + 1; t[3] = 2 * i + 2;
        wt[0] = 0.125f; wt[1] = 0.375f; wt[2] = 0.375f; wt[3] = 0.125f;
    }
}

__global__ __launch_bounds__(256)
void downsample2x_kernel(const float* __restrict__ src, float* __restrict__ dst,
                         int BC, float mul) {
    int idx = blockIdx.x * blockDim.x + threadIdx.x;
    if (idx >= BC * HWF) return;
    int j = idx & (FW - 1);
    int i = (idx >> 8) & (FH - 1);
    int bc = idx >> 16;

    int tx[4], ty[4];
    float wx[4], wy[4];
    ds_taps(j, IW, tx, wx);
    ds_taps(i, IH, ty, wy);
    const float* s = src + (size_t)bc * HWI;
    float acc = 0.f;
    #pragma unroll
    for (int a = 0; a < 4; a++) {
        if (wy[a] == 0.f) continue;
        const float* rp = s + (size_t)ty[a] * IW;
        float row = wx[0] * rp[tx[0]] + wx[1] * rp[tx[1]] + wx[2] * rp[tx[2]] + wx[3] * rp[tx[3]];
        acc += wy[a] * row;
    }
    dst[idx] = acc * mul;
}

// ---------------------------------------------------------------------------
// img downsample -> channels-last bf16 xin slots [96..128)
// ---------------------------------------------------------------------------
__global__ __launch_bounds__(256)
void imgdown_cl_kernel(const float* __restrict__ out1, short* __restrict__ xin) {
    int idx = blockIdx.x * blockDim.x + threadIdx.x;
    if (idx >= NB * HWF) return;
    int j = idx & (FW - 1);
    int i = (idx >> 8) & (FH - 1);
    int b = idx >> 16;

    int tx[4], ty[4];
    float wx[4], wy[4];
    ds_taps(j, IW, tx, wx);
    ds_taps(i, IH, ty, wy);
    const float* s = out1 + (size_t)b * 3 * HWI;
    float acc[3] = {0.f, 0.f, 0.f};
    #pragma unroll
    for (int a = 0; a < 4; a++) {
        if (wy[a] == 0.f) continue;
        #pragma unroll
        for (int c = 0; c < 3; c++) {
            const float* rp = s + (size_t)c * HWI + (size_t)ty[a] * IW;
            float row = wx[0] * rp[tx[0]] + wx[1] * rp[tx[1]] + wx[2] * rp[tx[2]] + wx[3] * rp[tx[3]];
            acc[c] += wy[a] * row;
        }
    }
    short* dst = xin + ((size_t)(b * FH + i) * FW + j) * 128 + 96;
    s8v g0 = { (short)f2bf(acc[0]), (short)f2bf(acc[1]), (short)f2bf(acc[2]), 0, 0, 0, 0, 0 };
    s8v z  = { 0, 0, 0, 0, 0, 0, 0, 0 };
    *(s8v*)(dst)      = g0;
    *(s8v*)(dst + 8)  = z;
    *(s8v*)(dst + 16) = z;
    *(s8v*)(dst + 24) = z;
}

// ---------------------------------------------------------------------------
// feat [B][96][H][W] fp32 -> featT [B][H][W][96] channels-last (validated R1)
// ---------------------------------------------------------------------------
template <int BF>
__global__ __launch_bounds__(256)
void feat_cl_kernel(const float* __restrict__ feat, void* __restrict__ featT) {
    __shared__ float tile[64 * 97];
    int blk = blockIdx.x;                 // NB * (HWF/64) = 4096
    int b = blk >> 10;                    // HWF/64 = 1024
    int p0 = (blk & 1023) << 6;
    int t = threadIdx.x;
    {
        int px = t & 63, cq = t >> 6;     // cq: 4 groups of 24 channels
        const float* src = feat + (size_t)b * CF * HWF + p0 + px;
        #pragma unroll
        for (int k = 0; k < 24; k++) {
            int c = cq * 24 + k;
            tile[px * 97 + c] = src[(size_t)c * HWF];
        }
    }
    __syncthreads();
    int pxo = t >> 2, co = (t & 3) * 24;  // 4 threads per pixel, 24 ch each
    const float* trow = &tile[pxo * 97 + co];
    size_t obase = ((size_t)(b * HWF) + p0 + pxo) * 96 + co;
    if (BF) {
        short* dst = (short*)featT + obase;
        #pragma unroll
        for (int q = 0; q < 3; q++) {
            s8v pk;
            #pragma unroll
            for (int e = 0; e < 8; e++) pk[e] = (short)f2bf(trow[q * 8 + e]);
            *(s8v*)(dst + q * 8) = pk;
        }
    } else {
        float* dst = (float*)featT + obase;
        #pragma unroll
        for (int q = 0; q < 6; q++) {
            f4v vv = { trow[q * 4 + 0], trow[q * 4 + 1], trow[q * 4 + 2], trow[q * 4 + 3] };
            *(f4v*)(dst + q * 4) = vv;
        }
    }
}

// ---------------------------------------------------------------------------
// backward_warp(features) v3 over channels-last featT (validated R1)
// ---------------------------------------------------------------------------
template <int BF>
__global__ __launch_bounds__(256)
void warp_feat_cl2_kernel(const void* __restrict__ featT,
                          const float* __restrict__ flow_s,
                          float* __restrict__ wfeat,
                          short* __restrict__ xin) {
    int t = blockIdx.x * 256 + threadIdx.x;   // [0, NB*HWF*8)
    int g = t & 7;                            // channel group: 12 channels
    int pix = t >> 3;                         // [0, NB*HWF)
    int j = pix & (FW - 1);
    int i = (pix >> 8) & (FH - 1);
    int b = pix >> 16;

    float fx = flow_s[((size_t)b * 2 + 0) * HWF + i * FW + j];
    float fy = flow_s[((size_t)b * 2 + 1) * HWF + i * FW + j];
    float u = (float)j + 0.5f * fx;
    float v = (float)i + 0.5f * fy;
    bool valid = (u >= 0.f) && (u <= (float)(FW - 1)) && (v >= 0.f) && (v <= (float)(FH - 1));
    float x = fminf(fmaxf(u, 0.f), (float)(FW - 1));
    float y = fminf(fmaxf(v, 0.f), (float)(FH - 1));
    int x0 = min((int)x, FW - 2);
    int y0 = min((int)y, FH - 2);
    float wxf = x - (float)x0, wyf = y - (float)y0;
    float w00 = (1.f - wxf) * (1.f - wyf), w01 = wxf * (1.f - wyf);
    float w10 = (1.f - wxf) * wyf, w11 = wxf * wyf;
    if (!valid) { w00 = w01 = w10 = w11 = 0.f; }

    size_t base = ((size_t)(b * HWF) + (size_t)y0 * FW + x0) * 96 + g * 12;
    float vals[12];
    if (BF) {
        const short* fp = (const short*)featT + base;
        #pragma unroll
        for (int q = 0; q < 3; q++) {
            s4v a0 = *(const s4v*)(fp + q * 4);
            s4v a1 = *(const s4v*)(fp + 96 + q * 4);
            s4v a2 = *(const s4v*)(fp + 96 * FW + q * 4);
            s4v a3 = *(const s4v*)(fp + 96 * FW + 96 + q * 4);
            #pragma unroll
            for (int e = 0; e < 4; e++)
                vals[q * 4 + e] = w00 * bf2f(a0[e]) + w01 * bf2f(a1[e])
                                + w10 * bf2f(a2[e]) + w11 * bf2f(a3[e]);
        }
    } else {
        const float* fp = (const float*)featT + base;
        #pragma unroll
        for (int q = 0; q < 3; q++) {
            f4v a0 = *(const f4v*)(fp + q * 4);
            f4v a1 = *(const f4v*)(fp + 96 + q * 4);
            f4v a2 = *(const f4v*)(fp + 96 * FW + q * 4);
            f4v a3 = *(const f4v*)(fp + 96 * FW + 96 + q * 4);
            #pragma unroll
            for (int e = 0; e < 4; e++)
                vals[q * 4 + e] = w00 * a0[e] + w01 * a1[e] + w10 * a2[e] + w11 * a3[e];
        }
    }

    float* ob = wfeat + ((size_t)b * CF + g * 12) * HWF + (size_t)i * FW + j;
    #pragma unroll
    for (int k = 0; k < 12; k++) ob[(size_t)k * HWF] = vals[k];

    short* xr = xin + (size_t)pix * 128 + g * 12;   // 24B per thread, 8B-aligned
    #pragma unroll
    for (int q2 = 0; q2 < 3; q2++) {
        s4v pk = { (short)f2bf(vals[q2 * 4 + 0]), (short)f2bf(vals[q2 * 4 + 1]),
                   (short)f2bf(vals[q2 * 4 + 2]), (short)f2bf(vals[q2 * 4 + 3]) };
        *(s4v*)(xr + q2 * 4) = pk;
    }
}

// ---------------------------------------------------------------------------
// backward_warp(features) v2 — kept as workspace-size fallback
// ---------------------------------------------------------------------------
__global__ __launch_bounds__(256)
void warp_feat_cl_kernel(const float* __restrict__ feat,
                         const float* __restrict__ flow_s,
                         float* __restrict__ wfeat,
                         short* __restrict__ xin) {
    int t = blockIdx.x * 256 + threadIdx.x;   // [0, NB*HWF*8)
    int g = t & 7;                            // channel group: 12 channels
    int pix = t >> 3;                         // [0, NB*HWF)
    int j = pix & (FW - 1);
    int i = (pix >> 8) & (FH - 1);
    int b = pix >> 16;

    float fx = flow_s[((size_t)b * 2 + 0) * HWF + i * FW + j];
    float fy = flow_s[((size_t)b * 2 + 1) * HWF + i * FW + j];
    float u = (float)j + 0.5f * fx;
    float v = (float)i + 0.5f * fy;
    bool valid = (u >= 0.f) && (u <= (float)(FW - 1)) && (v >= 0.f) && (v <= (float)(FH - 1));
    float x = fminf(fmaxf(u, 0.f), (float)(FW - 1));
    float y = fminf(fmaxf(v, 0.f), (float)(FH - 1));
    int x0 = min((int)x, FW - 2);
    int y0 = min((int)y, FH - 2);
    float wxf = x - (float)x0, wyf = y - (float)y0;
    float w00 = (1.f - wxf) * (1.f - wyf), w01 = wxf * (1.f - wyf);
    float w10 = (1.f - wxf) * wyf, w11 = wxf * wyf;
    if (!valid) { w00 = w01 = w10 = w11 = 0.f; }

    const float* fb = feat + ((size_t)b * CF + g * 12) * HWF + (size_t)y0 * FW + x0;
    float vals[12];
    #pragma unroll
    for (int k = 0; k < 12; k++) {
        const float* p = fb + (size_t)k * HWF;
        f2v r0 = *(const f2v*)p;
        f2v r1 = *(const f2v*)(p + FW);
        vals[k] = w00 * r0.x + w01 * r0.y + w10 * r1.x + w11 * r1.y;
    }

    float* ob = wfeat + ((size_t)b * CF + g * 12) * HWF + (size_t)i * FW + j;
    #pragma unroll
    for (int k = 0; k < 12; k++) ob[(size_t)k * HWF] = vals[k];

    short* xr = xin + (size_t)pix * 128 + g * 12;   // 24B per thread, 8B-aligned
    #pragma unroll
    for (int q2 = 0; q2 < 3; q2++) {
        s4v pk = { (short)f2bf(vals[q2 * 4 + 0]), (short)f2bf(vals[q2 * 4 + 1]),
                   (short)f2bf(vals[q2 * 4 + 2]), (short)f2bf(vals[q2 * 4 + 3]) };
        *(s4v*)(xr + q2 * 4) = pk;
    }
}

// ---------------------------------------------------------------------------
// Weight repack: w[co][ci][3][3] fp32 -> wA[kc][dy][dx][co][32ci] bf16.
// Per conv step (kc,dy) the A tile (3dx*96co*32ci = 18,432B) is contiguous.
// cvt_w1 also zeroes the 256B zero-page (DMA source for OOB lanes).
// ---------------------------------------------------------------------------
__global__ __launch_bounds__(256)
void cvt_w1_kernel(const float* __restrict__ w1, short* __restrict__ wA1,
                   short* __restrict__ zpage) {
    int i = blockIdx.x * 256 + threadIdx.x;
    if (i < 128) zpage[i] = 0;
    if (i >= 4 * 3 * 3 * 96 * 32) return;
    int cl = i & 31;
    int co = (i >> 5) % 96;
    int rest = i / 3072;
    int dx = rest % 3;
    int dy = (rest / 3) % 3;
    int kc = rest / 9;
    int ci = kc * 32 + cl;
    float v = (ci < C1) ? w1[((size_t)co * C1 + ci) * 9 + dy * 3 + dx] : 0.f;
    wA1[i] = (short)f2bf(v);
}
__global__ __launch_bounds__(256)
void cvt_w2_kernel(const float* __restrict__ w2, short* __restrict__ wA2) {
    int i = blockIdx.x * 256 + threadIdx.x;
    if (i >= 3 * 3 * 3 * 96 * 32) return;
    int cl = i & 31;
    int co = (i >> 5) % 96;
    int rest = i / 3072;
    int dx = rest % 3;
    int dy = (rest / 3) % 3;
    int kc = rest / 9;
    wA2[i] = (short)f2bf(w2[((size_t)co * CF + kc * 32 + cl) * 9 + dy * 3 + dx]);
}

// ---------------------------------------------------------------------------
// MFMA implicit-GEMM 3x3 conv v4: global_load_lds DMA staging.
// No register staging -> nothing to spill (R2/R3 root cause). LDS rows are
// unpadded 64B (DMA needs linear dest); all ds_read_b128 patterns are then
// lane-contiguous 1024B/wave -> bank-conflict-free. OOB lanes (halo px /
// invalid row) DMA from a 16B zero page. __syncthreads drains vmcnt(0)
// guaranteeing DMA completion; 4-5 blocks/CU of TLP hides the drain.
// Per step: A tile = 18 KiB contiguous (5 uniform issues/wave, chunks >=18
// are dummies into slack rows), B tile = 130 halo px (3 uniform issues/wave,
// 4 lanes per pixel). 36 MFMAs per barrier pair.
// ---------------------------------------------------------------------------
template <int PASS>
__global__ __launch_bounds__(256)
void conv_mfma4_kernel(const short* __restrict__ X,    // [b][h][w][KSTR] bf16
                       const short* __restrict__ W,    // [KC][3dy][3dx][96co][32ci] bf16
                       const float* __restrict__ bias,
                       const short* __restrict__ zpage,
                       short* __restrict__ t1out,
                       float* __restrict__ out0) {
    constexpr int KSTR = (PASS == 1) ? 128 : 96;
    constexpr int KC = KSTR / 32;
    __shared__ short Als[320 * 32];    // 20480 B: rows 0..287 used, 288.. slack
    __shared__ short Bls[192 * 32];    // 12288 B: halo px 0..129 used

    const int bx = blockIdx.x;
    const int w0 = (bx & 1) * 128;
    const int h  = (bx >> 1) & (FH - 1);
    const int b  = bx >> 9;

    const int tid = threadIdx.x;
    const int lane = tid & 63;
    const int wv = tid >> 6;
    const int ln = lane & 15;
    const int q  = lane >> 4;

    f4v acc[6][2];
    #pragma unroll
    for (int mt = 0; mt < 6; mt++)
        #pragma unroll
        for (int nt = 0; nt < 2; nt++)
            acc[mt][nt] = (f4v){0.f, 0.f, 0.f, 0.f};

    const short* Xb = X + (size_t)(b * FH) * FW * KSTR;
    const int bpx = wv * 48 + (lane >> 2);   // B: pixel handled by this lane (+k*16)
    const int bch = lane & 3;                // B: 16B chunk within pixel's 64B slice

    for (int kc = 0; kc < KC; ++kc) {
        for (int dy = 0; dy < 3; ++dy) {
            const int step = kc * 3 + dy;
            const int hy = h + dy - 1;
            const bool hok = (hy >= 0) && (hy < FH);
            const short* Xrow = Xb + (size_t)(hok ? hy : 0) * FW * KSTR + kc * 32;
            const short* Wstep = W + (size_t)step * 288 * 32;

            __syncthreads();   // prev compute's LDS reads done
            // ---- A DMA: 5 uniform issues/wave, 1024B each ----
            #pragma unroll
            for (int k = 0; k < 5; k++) {
                int c = k * 4 + wv;                       // chunk 0..19 (18,19 dummy)
                const short* g = (c < 18) ? (Wstep + c * 512 + lane * 8) : zpage;
                gl_lds16(g, Als + c * 512);
            }
            // ---- B DMA: 3 uniform issues/wave, 16 px each ----
            #pragma unroll
            for (int k = 0; k < 3; k++) {
                int px = bpx + k * 16;                    // 0..191
                int wp = w0 - 1 + px;
                bool ok = hok && (px < 130) && (wp >= 0) && (wp < FW);
                const short* g = ok ? (Xrow + (size_t)wp * KSTR + bch * 8) : zpage;
                gl_lds16(g, Bls + (wv * 48 + k * 16) * 32);
            }
            __syncthreads();   // implicit vmcnt(0): DMA landed

            #pragma unroll
            for (int dx = 0; dx < 3; ++dx) {
                s8v bfr0 = *(const s8v*)(Bls + (wv * 32 + ln + dx) * 32 + q * 8);
                s8v bfr1 = *(const s8v*)(Bls + (wv * 32 + 16 + ln + dx) * 32 + q * 8);
                #pragma unroll
                for (int mt = 0; mt < 6; ++mt) {
                    s8v afr = *(const s8v*)(Als + (dx * 96 + mt * 16 + ln) * 32 + q * 8);
                    acc[mt][0] = __builtin_amdgcn_mfma_f32_16x16x32_bf16(afr, bfr0, acc[mt][0], 0, 0, 0);
                    acc[mt][1] = __builtin_amdgcn_mfma_f32_16x16x32_bf16(afr, bfr1, acc[mt][1], 0, 0, 0);
                }
            }
        }
    }

    if (PASS == 1) {
        const size_t rowbase = (size_t)(b * FH + h) * FW;
        #pragma unroll
        for (int nt = 0; nt < 2; ++nt) {
            int pos = w0 + wv * 32 + nt * 16 + ln;
            short* dst = t1out + (rowbase + pos) * CF;
            #pragma unroll
            for (int mt = 0; mt < 6; ++mt) {
                int co0 = mt * 16 + q * 4;
                s4v pk;
                #pragma unroll
                for (int r = 0; r < 4; ++r) {
                    float v = acc[mt][nt][r] + bias[co0 + r];
                    pk[r] = (short)f2bf(fmaxf(v, 0.f));
                }
                *(s4v*)(dst + co0) = pk;
            }
        }
    } else {
        #pragma unroll
        for (int nt = 0; nt < 2; ++nt) {
            int pos = w0 + wv * 32 + nt * 16 + ln;
            #pragma unroll
            for (int mt = 0; mt < 6; ++mt) {
                int co0 = mt * 16 + q * 4;
                #pragma unroll
                for (int r = 0; r < 4; ++r) {
                    size_t o = (size_t)(b * CF + co0 + r) * HWF + (size_t)h * FW + pos;
                    out0[o] += acc[mt][nt][r] + bias[co0 + r];
                }
            }
        }
    }
}

extern "C" void kernel_launch(void* const* d_in, const int* in_sizes, int n_in,
                              void* d_out, int out_size, void* d_ws, size_t ws_size,
                              hipStream_t stream) {
    const float* img  = (const float*)d_in[0];
    const float* feat = (const float*)d_in[1];
    const float* flow = (const float*)d_in[2];
    const float* kp   = (const float*)d_in[3];
    const float* w1   = (const float*)d_in[4];
    const float* b1   = (const float*)d_in[5];
    const float* w2   = (const float*)d_in[6];
    const float* b2   = (const float*)d_in[7];

    float* out0 = (float*)d_out;                       // [B,96,256,256] fp32
    float* out1 = out0 + (size_t)NB * CF * HWF;        // [B,3,512,512]  fp32

    char* wsb = (char*)d_ws;
    short* wA1 = (short*)wsb;                                   //   221,184 B
    short* wA2 = (short*)(wsb + 221184);                        //   165,888 B
    short* zpage = (short*)(wsb + 387072);                      //       256 B
    short* xin = (short*)(wsb + 387328);                        // 67,108,864 B [b][h][w][128]
    const size_t off_after_xin = 387328 + 67108864;             // 67,496,192

    const size_t FEATT_F32 = (size_t)NB * HWF * 96 * 4;         // 100,663,296
    const size_t FEATT_BF16 = (size_t)NB * HWF * 96 * 2;        //  50,331,648
    const size_t FLOW_B = 2097152;
    const size_t need_f32 = off_after_xin + FLOW_B + FEATT_F32;
    const size_t need_b16 = off_after_xin + FLOW_B + FEATT_BF16;

    int n_img = NB * HWI;
    hipLaunchKernelGGL(cvt_w1_kernel, dim3((9 * 96 * 128 + 255) / 256), dim3(256), 0, stream, w1, wA1, zpage);
    hipLaunchKernelGGL(cvt_w2_kernel, dim3((9 * 96 * 96 + 255) / 256), dim3(256), 0, stream, w2, wA2);

    if (ws_size >= need_b16) {
        // --- coalesced channels-last gather path ---
        const bool f32ok = (ws_size >= need_f32);
        float* flow_s = (float*)(wsb + off_after_xin);
        char* region  = wsb + off_after_xin + FLOW_B;
        // region timeline: img_row (lkw) -> featT (transpose+warp) -> t1cl (convs)
        float* img_row = (float*)region;
        void*  featT   = (void*)region;
        short* t1cl    = (short*)region;

        hipLaunchKernelGGL(lkw_row_kernel, dim3((n_img + 255) / 256), dim3(256), 0, stream,
                           img, flow, kp, img_row);
        hipLaunchKernelGGL(lkw_col_kernel, dim3((n_img + 255) / 256), dim3(256), 0, stream,
                           img_row, kp, out1);
        hipLaunchKernelGGL(downsample2x_kernel, dim3((NB * 2 * HWF + 255) / 256), dim3(256), 0, stream,
                           flow, flow_s, NB * 2, 0.5f);
        hipLaunchKernelGGL(imgdown_cl_kernel, dim3((NB * HWF + 255) / 256), dim3(256), 0, stream,
                           out1, xin);
        if (f32ok) {
            hipLaunchKernelGGL((feat_cl_kernel<0>), dim3(NB * (HWF / 64)), dim3(256), 0, stream,
                               feat, featT);
            hipLaunchKernelGGL((warp_feat_cl2_kernel<0>), dim3(NB * HWF * 8 / 256), dim3(256), 0, stream,
                               featT, flow_s, out0, xin);
        } else {
            hipLaunchKernelGGL((feat_cl_kernel<1>), dim3(NB * (HWF / 64)), dim3(256), 0, stream,
                               feat, featT);
            hipLaunchKernelGGL((warp_feat_cl2_kernel<1>), dim3(NB * HWF * 8 / 256), dim3(256), 0, stream,
                               featT, flow_s, out0, xin);
        }
        hipLaunchKernelGGL((conv_mfma4_kernel<1>), dim3(NB * FH * 2), dim3(256), 0, stream,
                           xin, wA1, b1, zpage, t1cl, (float*)nullptr);
        hipLaunchKernelGGL((conv_mfma4_kernel<2>), dim3(NB * FH * 2), dim3(256), 0, stream,
                           t1cl, wA2, b2, zpage, (short*)nullptr, out0);
    } else {
        // --- fallback (workspace too small for featT) ---
        char* region = wsb + off_after_xin;
        short* t1cl    = (short*)region;
        float* img_row = (float*)region;
        float* flow_s  = (float*)(region + 16777216);

        hipLaunchKernelGGL(lkw_row_kernel, dim3((n_img + 255) / 256), dim3(256), 0, stream,
                           img, flow, kp, img_row);
        hipLaunchKernelGGL(lkw_col_kernel, dim3((n_img + 255) / 256), dim3(256), 0, stream,
                           img_row, kp, out1);
        hipLaunchKernelGGL(downsample2x_kernel, dim3((NB * 2 * HWF + 255) / 256), dim3(256), 0, stream,
                           flow, flow_s, NB * 2, 0.5f);
        hipLaunchKernelGGL(imgdown_cl_kernel, dim3((NB * HWF + 255) / 256), dim3(256), 0, stream,
                           out1, xin);
        hipLaunchKernelGGL(warp_feat_cl_kernel, dim3(NB * HWF * 8 / 256), dim3(256), 0, stream,
                           feat, flow_s, out0, xin);
        hipLaunchKernelGGL((conv_mfma4_kernel<1>), dim3(NB * FH * 2), dim3(256), 0, stream,
                           xin, wA1, b1, zpage, t1cl, (float*)nullptr);
        hipLaunchKernelGGL((conv_mfma4_kernel<2>), dim3(NB * FH * 2), dim3(256), 0, stream,
                           t1cl, wA2, b2, zpage, (short*)nullptr, out0);
    }
}

// Round 5
// 580.516 us; speedup vs baseline: 1.3464x; 1.0440x over previous
//
#include <hip/hip_runtime.h>

#define NB 4
#define IH 512
#define IW 512
#define FH 256
#define FW 256
#define CF 96
#define C1 99
#define HWI (IH*IW)     /* 262144 */
#define HWF (FH*FW)     /* 65536  */

typedef short s8v __attribute__((ext_vector_type(8)));
typedef short s4v __attribute__((ext_vector_type(4)));
typedef float f4v __attribute__((ext_vector_type(4)));
typedef float f2v __attribute__((ext_vector_type(2), aligned(4)));  /* 4B-aligned pair load */

static __device__ __forceinline__ float sigmoidf_(float x) {
    return 1.0f / (1.0f + __expf(-x));
}
static __device__ __forceinline__ unsigned short f2bf(float f) {
    unsigned int u = __float_as_uint(f);
    unsigned int r = (u + 0x7fffu + ((u >> 16) & 1u)) >> 16;
    return (unsigned short)r;
}
static __device__ __forceinline__ float bf2f(short s) {
    unsigned int u = ((unsigned int)(unsigned short)s) << 16;
    return __uint_as_float(u);
}
// async global->LDS DMA, 16B per lane; LDS dest = wave-uniform base + lane*16
static __device__ __forceinline__ void gl_lds16(const short* g, short* l) {
    __builtin_amdgcn_global_load_lds(
        (const __attribute__((address_space(1))) void*)g,
        (__attribute__((address_space(3))) void*)l, 16, 0, 0);
}

// ---------------------------------------------------------------------------
// Pass 1 of local_kernel_warp (validated R1)
// ---------------------------------------------------------------------------
__global__ __launch_bounds__(256)
void lkw_row_kernel(const float* __restrict__ img,
                    const float* __restrict__ flow,
                    const float* __restrict__ kp,
                    float* __restrict__ img_row) {
    int idx = blockIdx.x * blockDim.x + threadIdx.x;
    if (idx >= NB * HWI) return;
    int w = idx & (IW - 1);
    int h = (idx >> 9) & (IH - 1);
    int b = idx >> 18;

    const float* kpb = kp + (size_t)b * 11 * HWI + h * IW + w;
    float p[5];
    float m = -1e30f;
    #pragma unroll
    for (int k = 0; k < 5; k++) { p[k] = kpb[k * HWI]; m = fmaxf(m, p[k]); }
    float s = 0.f;
    #pragma unroll
    for (int k = 0; k < 5; k++) { p[k] = __expf(p[k] - m); s += p[k]; }
    float invs = 1.f / s;
    float a = sigmoidf_(kpb[10 * HWI]) + 0.5f;
    float inva = 1.f / a;

    float fx = flow[((size_t)b * 2 + 0) * HWI + h * IW + w];
    float fy = flow[((size_t)b * 2 + 1) * HWI + h * IW + w];

    float y = (float)h + 0.5f * fy;
    y = fminf(fmaxf(y, 0.f), (float)(IH - 1));
    float y0f = floorf(y);
    int y0 = (int)y0f;
    int y1 = min(y0 + 1, IH - 1);
    float wy = y - y0f;

    float xbase = (float)w + 0.5f * fx;
    const float sc = (float)(IW - 1) / (float)IW;

    const float* imb = img + (size_t)b * 3 * HWI;
    float acc0 = 0.f, acc1 = 0.f, acc2 = 0.f;
    #pragma unroll
    for (int k = 0; k < 5; k++) {
        float x = xbase + (float)(k - 2) * inva * sc;
        x = fminf(fmaxf(x, 0.f), (float)(IW - 1));
        float x0f = floorf(x);
        int x0 = (int)x0f;
        int x1 = min(x0 + 1, IW - 1);
        float wx = x - x0f;
        float wk = p[k] * invs;
        float w00 = (1.f - wx) * (1.f - wy) * wk;
        float w01 = wx * (1.f - wy) * wk;
        float w10 = (1.f - wx) * wy * wk;
        float w11 = wx * wy * wk;
        int i00 = y0 * IW + x0, i01 = y0 * IW + x1;
        int i10 = y1 * IW + x0, i11 = y1 * IW + x1;
        acc0 += w00 * imb[i00] + w01 * imb[i01] + w10 * imb[i10] + w11 * imb[i11];
        acc1 += w00 * imb[HWI + i00] + w01 * imb[HWI + i01] + w10 * imb[HWI + i10] + w11 * imb[HWI + i11];
        acc2 += w00 * imb[2 * HWI + i00] + w01 * imb[2 * HWI + i01] + w10 * imb[2 * HWI + i10] + w11 * imb[2 * HWI + i11];
    }
    img_row[(size_t)b * 3 * HWI + h * IW + w] = acc0;
    img_row[(size_t)b * 3 * HWI + HWI + h * IW + w] = acc1;
    img_row[(size_t)b * 3 * HWI + 2 * HWI + h * IW + w] = acc2;
}

// ---------------------------------------------------------------------------
// Pass 2 (validated R1)
// ---------------------------------------------------------------------------
__global__ __launch_bounds__(256)
void lkw_col_kernel(const float* __restrict__ img_row,
                    const float* __restrict__ kp,
                    float* __restrict__ out1) {
    int idx = blockIdx.x * blockDim.x + threadIdx.x;
    if (idx >= NB * HWI) return;
    int w = idx & (IW - 1);
    int h = (idx >> 9) & (IH - 1);
    int b = idx >> 18;

    const float* kpb = kp + (size_t)b * 11 * HWI + h * IW + w;
    float p[5];
    float m = -1e30f;
    #pragma unroll
    for (int k = 0; k < 5; k++) { p[k] = kpb[(5 + k) * HWI]; m = fmaxf(m, p[k]); }
    float s = 0.f;
    #pragma unroll
    for (int k = 0; k < 5; k++) { p[k] = __expf(p[k] - m); s += p[k]; }
    float invs = 1.f / s;
    float a = sigmoidf_(kpb[10 * HWI]) + 0.5f;

    const float sc = (float)(IH - 1) / (float)IH;
    const float* irb = img_row + (size_t)b * 3 * HWI;
    float acc0 = 0.f, acc1 = 0.f, acc2 = 0.f;
    #pragma unroll
    for (int k = 0; k < 5; k++) {
        float y = (float)h + (float)(k - 2) * a * sc;
        y = fminf(fmaxf(y, 0.f), (float)(IH - 1));
        float y0f = floorf(y);
        int y0 = (int)y0f;
        int y1 = min(y0 + 1, IH - 1);
        float wy = y - y0f;
        float wk = p[k] * invs;
        float w0 = (1.f - wy) * wk, w1 = wy * wk;
        int i0 = y0 * IW + w, i1 = y1 * IW + w;
        acc0 += w0 * irb[i0] + w1 * irb[i1];
        acc1 += w0 * irb[HWI + i0] + w1 * irb[HWI + i1];
        acc2 += w0 * irb[2 * HWI + i0] + w1 * irb[2 * HWI + i1];
    }
    out1[(size_t)b * 3 * HWI + h * IW + w] = acc0;
    out1[(size_t)b * 3 * HWI + HWI + h * IW + w] = acc1;
    out1[(size_t)b * 3 * HWI + 2 * HWI + h * IW + w] = acc2;
}

// ---------------------------------------------------------------------------
// antialiased 2x downsample taps (validated R1)
// ---------------------------------------------------------------------------
static __device__ __forceinline__ void ds_taps(int i, int n_in, int t[4], float wt[4]) {
    int n_out = n_in >> 1;
    if (i == 0) {
        t[0] = 0; t[1] = 0; t[2] = 1; t[3] = 2;
        wt[0] = 0.f; wt[1] = 3.f / 7.f; wt[2] = 3.f / 7.f; wt[3] = 1.f / 7.f;
    } else if (i == n_out - 1) {
        t[0] = n_in - 3; t[1] = n_in - 2; t[2] = n_in - 1; t[3] = n_in - 1;
        wt[0] = 1.f / 7.f; wt[1] = 3.f / 7.f; wt[2] = 3.f / 7.f; wt[3] = 0.f;
    } else {
        t[0] = 2 * i - 1; t[1] = 2 * i; t[2] = 2 * i + 1; t[3] = 2 * i + 2;
        wt[0] = 0.125f; wt[1] = 0.375f; wt[2] = 0.375f; wt[3] = 0.125f;
    }
}

__global__ __launch_bounds__(256)
void downsample2x_kernel(const float* __restrict__ src, float* __restrict__ dst,
                         int BC, float mul) {
    int idx = blockIdx.x * blockDim.x + threadIdx.x;
    if (idx >= BC * HWF) return;
    int j = idx & (FW - 1);
    int i = (idx >> 8) & (FH - 1);
    int bc = idx >> 16;

    int tx[4], ty[4];
    float wx[4], wy[4];
    ds_taps(j, IW, tx, wx);
    ds_taps(i, IH, ty, wy);
    const float* s = src + (size_t)bc * HWI;
    float acc = 0.f;
    #pragma unroll
    for (int a = 0; a < 4; a++) {
        if (wy[a] == 0.f) continue;
        const float* rp = s + (size_t)ty[a] * IW;
        float row = wx[0] * rp[tx[0]] + wx[1] * rp[tx[1]] + wx[2] * rp[tx[2]] + wx[3] * rp[tx[3]];
        acc += wy[a] * row;
    }
    dst[idx] = acc * mul;
}

// ---------------------------------------------------------------------------
// img downsample -> channels-last bf16 xin slots [96..128)
// ---------------------------------------------------------------------------
__global__ __launch_bounds__(256)
void imgdown_cl_kernel(const float* __restrict__ out1, short* __restrict__ xin) {
    int idx = blockIdx.x * blockDim.x + threadIdx.x;
    if (idx >= NB * HWF) return;
    int j = idx & (FW - 1);
    int i = (idx >> 8) & (FH - 1);
    int b = idx >> 16;

    int tx[4], ty[4];
    float wx[4], wy[4];
    ds_taps(j, IW, tx, wx);
    ds_taps(i, IH, ty, wy);
    const float* s = out1 + (size_t)b * 3 * HWI;
    float acc[3] = {0.f, 0.f, 0.f};
    #pragma unroll
    for (int a = 0; a < 4; a++) {
        if (wy[a] == 0.f) continue;
        #pragma unroll
        for (int c = 0; c < 3; c++) {
            const float* rp = s + (size_t)c * HWI + (size_t)ty[a] * IW;
            float row = wx[0] * rp[tx[0]] + wx[1] * rp[tx[1]] + wx[2] * rp[tx[2]] + wx[3] * rp[tx[3]];
            acc[c] += wy[a] * row;
        }
    }
    short* dst = xin + ((size_t)(b * FH + i) * FW + j) * 128 + 96;
    s8v g0 = { (short)f2bf(acc[0]), (short)f2bf(acc[1]), (short)f2bf(acc[2]), 0, 0, 0, 0, 0 };
    s8v z  = { 0, 0, 0, 0, 0, 0, 0, 0 };
    *(s8v*)(dst)      = g0;
    *(s8v*)(dst + 8)  = z;
    *(s8v*)(dst + 16) = z;
    *(s8v*)(dst + 24) = z;
}

// ---------------------------------------------------------------------------
// feat [B][96][H][W] fp32 -> featT [B][H][W][96] channels-last (validated R1)
// ---------------------------------------------------------------------------
template <int BF>
__global__ __launch_bounds__(256)
void feat_cl_kernel(const float* __restrict__ feat, void* __restrict__ featT) {
    __shared__ float tile[64 * 97];
    int blk = blockIdx.x;                 // NB * (HWF/64) = 4096
    int b = blk >> 10;                    // HWF/64 = 1024
    int p0 = (blk & 1023) << 6;
    int t = threadIdx.x;
    {
        int px = t & 63, cq = t >> 6;     // cq: 4 groups of 24 channels
        const float* src = feat + (size_t)b * CF * HWF + p0 + px;
        #pragma unroll
        for (int k = 0; k < 24; k++) {
            int c = cq * 24 + k;
            tile[px * 97 + c] = src[(size_t)c * HWF];
        }
    }
    __syncthreads();
    int pxo = t >> 2, co = (t & 3) * 24;  // 4 threads per pixel, 24 ch each
    const float* trow = &tile[pxo * 97 + co];
    size_t obase = ((size_t)(b * HWF) + p0 + pxo) * 96 + co;
    if (BF) {
        short* dst = (short*)featT + obase;
        #pragma unroll
        for (int q = 0; q < 3; q++) {
            s8v pk;
            #pragma unroll
            for (int e = 0; e < 8; e++) pk[e] = (short)f2bf(trow[q * 8 + e]);
            *(s8v*)(dst + q * 8) = pk;
        }
    } else {
        float* dst = (float*)featT + obase;
        #pragma unroll
        for (int q = 0; q < 6; q++) {
            f4v vv = { trow[q * 4 + 0], trow[q * 4 + 1], trow[q * 4 + 2], trow[q * 4 + 3] };
            *(f4v*)(dst + q * 4) = vv;
        }
    }
}

// ---------------------------------------------------------------------------
// backward_warp(features) v3 over channels-last featT (validated R1)
// ---------------------------------------------------------------------------
template <int BF>
__global__ __launch_bounds__(256)
void warp_feat_cl2_kernel(const void* __restrict__ featT,
                          const float* __restrict__ flow_s,
                          float* __restrict__ wfeat,
                          short* __restrict__ xin) {
    int t = blockIdx.x * 256 + threadIdx.x;   // [0, NB*HWF*8)
    int g = t & 7;                            // channel group: 12 channels
    int pix = t >> 3;                         // [0, NB*HWF)
    int j = pix & (FW - 1);
    int i = (pix >> 8) & (FH - 1);
    int b = pix >> 16;

    float fx = flow_s[((size_t)b * 2 + 0) * HWF + i * FW + j];
    float fy = flow_s[((size_t)b * 2 + 1) * HWF + i * FW + j];
    float u = (float)j + 0.5f * fx;
    float v = (float)i + 0.5f * fy;
    bool valid = (u >= 0.f) && (u <= (float)(FW - 1)) && (v >= 0.f) && (v <= (float)(FH - 1));
    float x = fminf(fmaxf(u, 0.f), (float)(FW - 1));
    float y = fminf(fmaxf(v, 0.f), (float)(FH - 1));
    int x0 = min((int)x, FW - 2);
    int y0 = min((int)y, FH - 2);
    float wxf = x - (float)x0, wyf = y - (float)y0;
    float w00 = (1.f - wxf) * (1.f - wyf), w01 = wxf * (1.f - wyf);
    float w10 = (1.f - wxf) * wyf, w11 = wxf * wyf;
    if (!valid) { w00 = w01 = w10 = w11 = 0.f; }

    size_t base = ((size_t)(b * HWF) + (size_t)y0 * FW + x0) * 96 + g * 12;
    float vals[12];
    if (BF) {
        const short* fp = (const short*)featT + base;
        #pragma unroll
        for (int q = 0; q < 3; q++) {
            s4v a0 = *(const s4v*)(fp + q * 4);
            s4v a1 = *(const s4v*)(fp + 96 + q * 4);
            s4v a2 = *(const s4v*)(fp + 96 * FW + q * 4);
            s4v a3 = *(const s4v*)(fp + 96 * FW + 96 + q * 4);
            #pragma unroll
            for (int e = 0; e < 4; e++)
                vals[q * 4 + e] = w00 * bf2f(a0[e]) + w01 * bf2f(a1[e])
                                + w10 * bf2f(a2[e]) + w11 * bf2f(a3[e]);
        }
    } else {
        const float* fp = (const float*)featT + base;
        #pragma unroll
        for (int q = 0; q < 3; q++) {
            f4v a0 = *(const f4v*)(fp + q * 4);
            f4v a1 = *(const f4v*)(fp + 96 + q * 4);
            f4v a2 = *(const f4v*)(fp + 96 * FW + q * 4);
            f4v a3 = *(const f4v*)(fp + 96 * FW + 96 + q * 4);
            #pragma unroll
            for (int e = 0; e < 4; e++)
                vals[q * 4 + e] = w00 * a0[e] + w01 * a1[e] + w10 * a2[e] + w11 * a3[e];
        }
    }

    float* ob = wfeat + ((size_t)b * CF + g * 12) * HWF + (size_t)i * FW + j;
    #pragma unroll
    for (int k = 0; k < 12; k++) ob[(size_t)k * HWF] = vals[k];

    short* xr = xin + (size_t)pix * 128 + g * 12;   // 24B per thread, 8B-aligned
    #pragma unroll
    for (int q2 = 0; q2 < 3; q2++) {
        s4v pk = { (short)f2bf(vals[q2 * 4 + 0]), (short)f2bf(vals[q2 * 4 + 1]),
                   (short)f2bf(vals[q2 * 4 + 2]), (short)f2bf(vals[q2 * 4 + 3]) };
        *(s4v*)(xr + q2 * 4) = pk;
    }
}

// ---------------------------------------------------------------------------
// backward_warp(features) v2 — kept as workspace-size fallback
// ---------------------------------------------------------------------------
__global__ __launch_bounds__(256)
void warp_feat_cl_kernel(const float* __restrict__ feat,
                         const float* __restrict__ flow_s,
                         float* __restrict__ wfeat,
                         short* __restrict__ xin) {
    int t = blockIdx.x * 256 + threadIdx.x;   // [0, NB*HWF*8)
    int g = t & 7;                            // channel group: 12 channels
    int pix = t >> 3;                         // [0, NB*HWF)
    int j = pix & (FW - 1);
    int i = (pix >> 8) & (FH - 1);
    int b = pix >> 16;

    float fx = flow_s[((size_t)b * 2 + 0) * HWF + i * FW + j];
    float fy = flow_s[((size_t)b * 2 + 1) * HWF + i * FW + j];
    float u = (float)j + 0.5f * fx;
    float v = (float)i + 0.5f * fy;
    bool valid = (u >= 0.f) && (u <= (float)(FW - 1)) && (v >= 0.f) && (v <= (float)(FH - 1));
    float x = fminf(fmaxf(u, 0.f), (float)(FW - 1));
    float y = fminf(fmaxf(v, 0.f), (float)(FH - 1));
    int x0 = min((int)x, FW - 2);
    int y0 = min((int)y, FH - 2);
    float wxf = x - (float)x0, wyf = y - (float)y0;
    float w00 = (1.f - wxf) * (1.f - wyf), w01 = wxf * (1.f - wyf);
    float w10 = (1.f - wxf) * wyf, w11 = wxf * wyf;
    if (!valid) { w00 = w01 = w10 = w11 = 0.f; }

    const float* fb = feat + ((size_t)b * CF + g * 12) * HWF + (size_t)y0 * FW + x0;
    float vals[12];
    #pragma unroll
    for (int k = 0; k < 12; k++) {
        const float* p = fb + (size_t)k * HWF;
        f2v r0 = *(const f2v*)p;
        f2v r1 = *(const f2v*)(p + FW);
        vals[k] = w00 * r0.x + w01 * r0.y + w10 * r1.x + w11 * r1.y;
    }

    float* ob = wfeat + ((size_t)b * CF + g * 12) * HWF + (size_t)i * FW + j;
    #pragma unroll
    for (int k = 0; k < 12; k++) ob[(size_t)k * HWF] = vals[k];

    short* xr = xin + (size_t)pix * 128 + g * 12;   // 24B per thread, 8B-aligned
    #pragma unroll
    for (int q2 = 0; q2 < 3; q2++) {
        s4v pk = { (short)f2bf(vals[q2 * 4 + 0]), (short)f2bf(vals[q2 * 4 + 1]),
                   (short)f2bf(vals[q2 * 4 + 2]), (short)f2bf(vals[q2 * 4 + 3]) };
        *(s4v*)(xr + q2 * 4) = pk;
    }
}

// ---------------------------------------------------------------------------
// Weight repack: w[co][ci][3][3] fp32 -> wA[kc][dy][dx][co][32ci] bf16.
// Per conv step (kc,dy) the A tile (3dx*96co*32ci = 18,432B) is contiguous.
// cvt_w1 also zeroes the 256B zero-page (DMA source for OOB lanes).
// ---------------------------------------------------------------------------
__global__ __launch_bounds__(256)
void cvt_w1_kernel(const float* __restrict__ w1, short* __restrict__ wA1,
                   short* __restrict__ zpage) {
    int i = blockIdx.x * 256 + threadIdx.x;
    if (i < 128) zpage[i] = 0;
    if (i >= 4 * 3 * 3 * 96 * 32) return;
    int cl = i & 31;
    int co = (i >> 5) % 96;
    int rest = i / 3072;
    int dx = rest % 3;
    int dy = (rest / 3) % 3;
    int kc = rest / 9;
    int ci = kc * 32 + cl;
    float v = (ci < C1) ? w1[((size_t)co * C1 + ci) * 9 + dy * 3 + dx] : 0.f;
    wA1[i] = (short)f2bf(v);
}
__global__ __launch_bounds__(256)
void cvt_w2_kernel(const float* __restrict__ w2, short* __restrict__ wA2) {
    int i = blockIdx.x * 256 + threadIdx.x;
    if (i >= 3 * 3 * 3 * 96 * 32) return;
    int cl = i & 31;
    int co = (i >> 5) % 96;
    int rest = i / 3072;
    int dx = rest % 3;
    int dy = (rest / 3) % 3;
    int kc = rest / 9;
    wA2[i] = (short)f2bf(w2[((size_t)co * CF + kc * 32 + cl) * 9 + dy * 3 + dx]);
}

// ---------------------------------------------------------------------------
// MFMA implicit-GEMM 3x3 conv v5: v4's DMA staging + T3/T4 counted-vmcnt
// double-buffered pipeline (+T5 setprio). Per iter: issue next step's 8 DMAs
// into buf[(s+1)&1], s_waitcnt vmcnt(8) (waits ONLY step-s's loads; 8 stay
// in flight across the barrier), raw s_barrier, 36 MFMAs, raw s_barrier
// (gates next iter's re-stage of buf[(s+1)&1] -- two barriers/iter are
// required for write-after-read safety). Uniform 8 issues/wave/step makes
// the vmcnt arithmetic exact. Raw barriers avoid __syncthreads' vmcnt(0)
// drain (the m97/m233 2-phase stall).
// ---------------------------------------------------------------------------
template <int PASS>
__global__ __launch_bounds__(256)
void conv_mfma5_kernel(const short* __restrict__ X,    // [b][h][w][KSTR] bf16
                       const short* __restrict__ W,    // [KC][3dy][3dx][96co][32ci] bf16
                       const float* __restrict__ bias,
                       const short* __restrict__ zpage,
                       short* __restrict__ t1out,
                       float* __restrict__ out0) {
    constexpr int KSTR = (PASS == 1) ? 128 : 96;
    constexpr int KC = KSTR / 32;
    constexpr int NSTEP = KC * 3;
    __shared__ short Als[2][320 * 32];    // per buf: rows 0..287 used, 288.. slack
    __shared__ short Bls[2][192 * 32];    // per buf: halo px 0..129 used (max row read 129)

    const int bx = blockIdx.x;
    const int w0 = (bx & 1) * 128;
    const int h  = (bx >> 1) & (FH - 1);
    const int b  = bx >> 9;

    const int tid = threadIdx.x;
    const int lane = tid & 63;
    const int wv = tid >> 6;
    const int ln = lane & 15;
    const int q  = lane >> 4;

    f4v acc[6][2];
    #pragma unroll
    for (int mt = 0; mt < 6; mt++)
        #pragma unroll
        for (int nt = 0; nt < 2; nt++)
            acc[mt][nt] = (f4v){0.f, 0.f, 0.f, 0.f};

    const short* Xb = X + (size_t)(b * FH) * FW * KSTR;
    const int bpx = wv * 48 + (lane >> 2);   // B: pixel handled by this lane (+k*16)
    const int bch = lane & 3;                // B: 16B chunk within pixel's 64B slice

    // issue the 8 DMAs (5 A + 3 B) for step s into buf[s&1]
    auto issue = [&](int s) {
        const int kcn = s / 3, dyn = s - kcn * 3;
        const int bufn = s & 1;
        const int hy = h + dyn - 1;
        const bool hok = (hy >= 0) && (hy < FH);
        const short* Xrow = Xb + (size_t)(hok ? hy : 0) * FW * KSTR + kcn * 32;
        const short* Wstep = W + (size_t)s * 288 * 32;
        #pragma unroll
        for (int k = 0; k < 5; k++) {
            int c = k * 4 + wv;                       // chunk 0..19 (18,19 dummy)
            const short* g = (c < 18) ? (Wstep + c * 512 + lane * 8) : zpage;
            gl_lds16(g, &Als[bufn][c * 512]);
        }
        #pragma unroll
        for (int k = 0; k < 3; k++) {
            int px = bpx + k * 16;                    // 0..191
            int wp = w0 - 1 + px;
            bool ok = hok && (px < 130) && (wp >= 0) && (wp < FW);
            const short* g = ok ? (Xrow + (size_t)wp * KSTR + bch * 8) : zpage;
            gl_lds16(g, &Bls[bufn][(wv * 48 + k * 16) * 32]);
        }
    };

    issue(0);
    for (int s = 0; s < NSTEP; ++s) {
        if (s + 1 < NSTEP) {
            issue(s + 1);                              // +8 in flight -> 16
            asm volatile("s_waitcnt vmcnt(8)" ::: "memory");  // step-s landed
        } else {
            asm volatile("s_waitcnt vmcnt(0)" ::: "memory");  // final drain
        }
        __builtin_amdgcn_s_barrier();                  // everyone's step-s in LDS
        asm volatile("" ::: "memory");

        const short* Ab = &Als[s & 1][0];
        const short* Bb = &Bls[s & 1][0];
        __builtin_amdgcn_s_setprio(1);
        #pragma unroll
        for (int dx = 0; dx < 3; ++dx) {
            s8v bfr0 = *(const s8v*)(Bb + (wv * 32 + ln + dx) * 32 + q * 8);
            s8v bfr1 = *(const s8v*)(Bb + (wv * 32 + 16 + ln + dx) * 32 + q * 8);
            #pragma unroll
            for (int mt = 0; mt < 6; ++mt) {
                s8v afr = *(const s8v*)(Ab + (dx * 96 + mt * 16 + ln) * 32 + q * 8);
                acc[mt][0] = __builtin_amdgcn_mfma_f32_16x16x32_bf16(afr, bfr0, acc[mt][0], 0, 0, 0);
                acc[mt][1] = __builtin_amdgcn_mfma_f32_16x16x32_bf16(afr, bfr1, acc[mt][1], 0, 0, 0);
            }
        }
        __builtin_amdgcn_s_setprio(0);
        asm volatile("" ::: "memory");
        __builtin_amdgcn_s_barrier();                  // all reads of buf[s&1] done
    }

    if (PASS == 1) {
        const size_t rowbase = (size_t)(b * FH + h) * FW;
        #pragma unroll
        for (int nt = 0; nt < 2; ++nt) {
            int pos = w0 + wv * 32 + nt * 16 + ln;
            short* dst = t1out + (rowbase + pos) * CF;
            #pragma unroll
            for (int mt = 0; mt < 6; ++mt) {
                int co0 = mt * 16 + q * 4;
                s4v pk;
                #pragma unroll
                for (int r = 0; r < 4; ++r) {
                    float v = acc[mt][nt][r] + bias[co0 + r];
                    pk[r] = (short)f2bf(fmaxf(v, 0.f));
                }
                *(s4v*)(dst + co0) = pk;
            }
        }
    } else {
        #pragma unroll
        for (int nt = 0; nt < 2; ++nt) {
            int pos = w0 + wv * 32 + nt * 16 + ln;
            #pragma unroll
            for (int mt = 0; mt < 6; ++mt) {
                int co0 = mt * 16 + q * 4;
                #pragma unroll
                for (int r = 0; r < 4; ++r) {
                    size_t o = (size_t)(b * CF + co0 + r) * HWF + (size_t)h * FW + pos;
                    out0[o] += acc[mt][nt][r] + bias[co0 + r];
                }
            }
        }
    }
}

extern "C" void kernel_launch(void* const* d_in, const int* in_sizes, int n_in,
                              void* d_out, int out_size, void* d_ws, size_t ws_size,
                              hipStream_t stream) {
    const float* img  = (const float*)d_in[0];
    const float* feat = (const float*)d_in[1];
    const float* flow = (const float*)d_in[2];
    const float* kp   = (const float*)d_in[3];
    const float* w1   = (const float*)d_in[4];
    const float* b1   = (const float*)d_in[5];
    const float* w2   = (const float*)d_in[6];
    const float* b2   = (const float*)d_in[7];

    float* out0 = (float*)d_out;                       // [B,96,256,256] fp32
    float* out1 = out0 + (size_t)NB * CF * HWF;        // [B,3,512,512]  fp32

    char* wsb = (char*)d_ws;
    short* wA1 = (short*)wsb;                                   //   221,184 B
    short* wA2 = (short*)(wsb + 221184);                        //   165,888 B
    short* zpage = (short*)(wsb + 387072);                      //       256 B
    short* xin = (short*)(wsb + 387328);                        // 67,108,864 B [b][h][w][128]
    const size_t off_after_xin = 387328 + 67108864;             // 67,496,192

    const size_t FEATT_F32 = (size_t)NB * HWF * 96 * 4;         // 100,663,296
    const size_t FEATT_BF16 = (size_t)NB * HWF * 96 * 2;        //  50,331,648
    const size_t FLOW_B = 2097152;
    const size_t need_f32 = off_after_xin + FLOW_B + FEATT_F32;
    const size_t need_b16 = off_after_xin + FLOW_B + FEATT_BF16;

    int n_img = NB * HWI;
    hipLaunchKernelGGL(cvt_w1_kernel, dim3((9 * 96 * 128 + 255) / 256), dim3(256), 0, stream, w1, wA1, zpage);
    hipLaunchKernelGGL(cvt_w2_kernel, dim3((9 * 96 * 96 + 255) / 256), dim3(256), 0, stream, w2, wA2);

    if (ws_size >= need_b16) {
        // --- coalesced channels-last gather path ---
        const bool f32ok = (ws_size >= need_f32);
        float* flow_s = (float*)(wsb + off_after_xin);
        char* region  = wsb + off_after_xin + FLOW_B;
        // region timeline: img_row (lkw) -> featT (transpose+warp) -> t1cl (convs)
        float* img_row = (float*)region;
        void*  featT   = (void*)region;
        short* t1cl    = (short*)region;

        hipLaunchKernelGGL(lkw_row_kernel, dim3((n_img + 255) / 256), dim3(256), 0, stream,
                           img, flow, kp, img_row);
        hipLaunchKernelGGL(lkw_col_kernel, dim3((n_img + 255) / 256), dim3(256), 0, stream,
                           img_row, kp, out1);
        hipLaunchKernelGGL(downsample2x_kernel, dim3((NB * 2 * HWF + 255) / 256), dim3(256), 0, stream,
                           flow, flow_s, NB * 2, 0.5f);
        hipLaunchKernelGGL(imgdown_cl_kernel, dim3((NB * HWF + 255) / 256), dim3(256), 0, stream,
                           out1, xin);
        if (f32ok) {
            hipLaunchKernelGGL((feat_cl_kernel<0>), dim3(NB * (HWF / 64)), dim3(256), 0, stream,
                               feat, featT);
            hipLaunchKernelGGL((warp_feat_cl2_kernel<0>), dim3(NB * HWF * 8 / 256), dim3(256), 0, stream,
                               featT, flow_s, out0, xin);
        } else {
            hipLaunchKernelGGL((feat_cl_kernel<1>), dim3(NB * (HWF / 64)), dim3(256), 0, stream,
                               feat, featT);
            hipLaunchKernelGGL((warp_feat_cl2_kernel<1>), dim3(NB * HWF * 8 / 256), dim3(256), 0, stream,
                               featT, flow_s, out0, xin);
        }
        hipLaunchKernelGGL((conv_mfma5_kernel<1>), dim3(NB * FH * 2), dim3(256), 0, stream,
                           xin, wA1, b1, zpage, t1cl, (float*)nullptr);
        hipLaunchKernelGGL((conv_mfma5_kernel<2>), dim3(NB * FH * 2), dim3(256), 0, stream,
                           t1cl, wA2, b2, zpage, (short*)nullptr, out0);
    } else {
        // --- fallback (workspace too small for featT) ---
        char* region = wsb + off_after_xin;
        short* t1cl    = (short*)region;
        float* img_row = (float*)region;
        float* flow_s  = (float*)(region + 16777216);

        hipLaunchKernelGGL(lkw_row_kernel, dim3((n_img + 255) / 256), dim3(256), 0, stream,
                           img, flow, kp, img_row);
        hipLaunchKernelGGL(lkw_col_kernel, dim3((n_img + 255) / 256), dim3(256), 0, stream,
                           img_row, kp, out1);
        hipLaunchKernelGGL(downsample2x_kernel, dim3((NB * 2 * HWF + 255) / 256), dim3(256), 0, stream,
                           flow, flow_s, NB * 2, 0.5f);
        hipLaunchKernelGGL(imgdown_cl_kernel, dim3((NB * HWF + 255) / 256), dim3(256), 0, stream,
                           out1, xin);
        hipLaunchKernelGGL(warp_feat_cl_kernel, dim3(NB * HWF * 8 / 256), dim3(256), 0, stream,
                           feat, flow_s, out0, xin);
        hipLaunchKernelGGL((conv_mfma5_kernel<1>), dim3(NB * FH * 2), dim3(256), 0, stream,
                           xin, wA1, b1, zpage, t1cl, (float*)nullptr);
        hipLaunchKernelGGL((conv_mfma5_kernel<2>), dim3(NB * FH * 2), dim3(256), 0, stream,
                           t1cl, wA2, b2, zpage, (short*)nullptr, out0);
    }
}